// Round 16
// baseline (311.518 us; speedup 1.0000x reference)
//
#include <hip/hip_runtime.h>
#include <hip/hip_bf16.h>
#include <hip/hip_fp16.h>

typedef _Float16 f16x8 __attribute__((ext_vector_type(8)));
typedef _Float16 f16x4 __attribute__((ext_vector_type(4)));
typedef float f32x4 __attribute__((ext_vector_type(4)));

#define T_TOK 8192
#define DIM   1024
#define FF    4096
#define NE    8
#define CAP   1024

// ---------------------------------------------------------------------------
// async global->LDS 16B copy. LDS dest = wave-uniform base + lane*16 (HW);
// global src is per-lane.
// ---------------------------------------------------------------------------
__device__ __forceinline__ void cp16(_Float16* lds, const _Float16* g) {
  __builtin_amdgcn_global_load_lds(
      (const __attribute__((address_space(1))) unsigned int*)(const void*)g,
      (__attribute__((address_space(3))) unsigned int*)(void*)lds, 16, 0, 0);
}

// ---------------------------------------------------------------------------
// Router (proven)
// ---------------------------------------------------------------------------
__global__ __launch_bounds__(256) void moe_router(
    const float* __restrict__ x, const float* __restrict__ Wr,
    int* __restrict__ top, float* __restrict__ topw)
{
  __shared__ float sWr[DIM * 9];
  const int tid = threadIdx.x;
  for (int i = tid; i < DIM * NE; i += 256) {
    int d = i >> 3, e = i & 7;
    sWr[d * 9 + e] = Wr[i];
  }
  __syncthreads();
  const int lane = tid & 63, w = tid >> 6;
  for (int t = 0; t < 4; ++t) {
    const int token = blockIdx.x * 16 + w * 4 + t;
    float acc[8] = {0.f, 0.f, 0.f, 0.f, 0.f, 0.f, 0.f, 0.f};
    for (int j = 0; j < 16; ++j) {
      float xv = x[(size_t)token * DIM + j * 64 + lane];
      const float* wr = &sWr[(j * 64 + lane) * 9];
#pragma unroll
      for (int e = 0; e < 8; ++e) acc[e] += xv * wr[e];
    }
#pragma unroll
    for (int e = 0; e < 8; ++e) {
#pragma unroll
      for (int off = 32; off > 0; off >>= 1)
        acc[e] += __shfl_xor(acc[e], off, 64);
    }
    if (lane == 0) {
      float m = acc[0];
#pragma unroll
      for (int e = 1; e < 8; ++e) m = fmaxf(m, acc[e]);
      float s = 0.f;
#pragma unroll
      for (int e = 0; e < 8; ++e) s += expf(acc[e] - m);
      int bi = 0; float bv = acc[0];
#pragma unroll
      for (int e = 1; e < 8; ++e) { if (acc[e] > bv) { bv = acc[e]; bi = e; } }
      top[token]  = bi;
      topw[token] = 1.0f / s;
    }
  }
}

// ---------------------------------------------------------------------------
// Order-preserving dispatch (proven, 1024 thr)
// ---------------------------------------------------------------------------
__global__ __launch_bounds__(1024) void moe_scan(
    const int* __restrict__ top, int* __restrict__ idx)
{
  __shared__ int running[8];
  __shared__ int wcnt[16][8];
  __shared__ int wpre[16][8];
  __shared__ int cbase[8];
  const int tid = threadIdx.x, lane = tid & 63, w = tid >> 6;
  for (int i = tid; i < NE * CAP; i += 1024) idx[i] = T_TOK;
  if (tid < 8) running[tid] = 0;
  __syncthreads();
  for (int chunk = 0; chunk < T_TOK / 1024; ++chunk) {
    const int tok = chunk * 1024 + tid;
    const int e = top[tok];
    unsigned long long mymask = 0ull;
#pragma unroll
    for (int ee = 0; ee < 8; ++ee) {
      unsigned long long m = __ballot(e == ee);
      if (ee == e) mymask = m;
      if (lane == ee) wcnt[w][ee] = __builtin_popcountll(m);
    }
    const int rankw = __builtin_popcountll(mymask & ((1ull << lane) - 1ull));
    __syncthreads();
    if (tid < 8) {
      int s = 0;
#pragma unroll
      for (int ww = 0; ww < 16; ++ww) { wpre[ww][tid] = s; s += wcnt[ww][tid]; }
      cbase[tid] = running[tid];
      running[tid] += s;
    }
    __syncthreads();
    const int rank = cbase[e] + wpre[w][e] + rankw;
    if (rank < CAP) idx[e * CAP + rank] = tok;
  }
}

// ---------------------------------------------------------------------------
// Fused: xg image (bid < 512) + W1 image (bid >= 512). (proven)
// ---------------------------------------------------------------------------
__global__ __launch_bounds__(256) void xg_w1(
    const float* __restrict__ x, const int* __restrict__ idx,
    _Float16* __restrict__ xgimg,
    const float* __restrict__ W1, _Float16* __restrict__ w1img)
{
  __shared__ _Float16 sT[64 * 256];   // 32 KB (W1 path)
  const int tid = threadIdx.x, bid = blockIdx.x;
  if (bid < 512) {
    const int kt = bid & 15, mt = (bid >> 4) & 3, e = bid >> 6;
    const int tok = idx[e * CAP + mt * 256 + tid];
    _Float16* dst = xgimg + (size_t)((e * 4 + mt) * 16 + kt) * 16384 + (size_t)tid * 64;
    if (tok < T_TOK) {
      const f32x4* src = (const f32x4*)(x + (size_t)tok * DIM + kt * 64);
      f32x4 v[16];
#pragma unroll
      for (int i = 0; i < 16; ++i) v[i] = src[i];
#pragma unroll
      for (int g = 0; g < 8; ++g) {
        f16x8 h;
#pragma unroll
        for (int c = 0; c < 4; ++c) {
          h[c]     = (_Float16)v[2 * g][c];
          h[4 + c] = (_Float16)v[2 * g + 1][c];
        }
        *(f16x8*)(dst + ((g ^ (tid & 7)) * 8)) = h;
      }
    } else {
      f16x8 z = {};
#pragma unroll
      for (int g = 0; g < 8; ++g) *(f16x8*)(dst + g * 8) = z;
    }
    return;
  }
  const int b = bid - 512;                      // 0..2047
  const int kt = b & 15, nt = (b >> 4) & 15, e = b >> 8;
  const float* src = W1 + (size_t)e * DIM * FF + (size_t)(kt * 64) * FF + nt * 256;
#pragma unroll
  for (int i = 0; i < 16; ++i) {
    const int q = i * 256 + tid;
    const int row = q >> 6, c4 = (q & 63) * 4;
    f32x4 u = *(const f32x4*)(src + (size_t)row * FF + c4);
    f16x4 h;
#pragma unroll
    for (int c = 0; c < 4; ++c) h[c] = (_Float16)u[c];
    *(f16x4*)&sT[row * 256 + c4] = h;
  }
  __syncthreads();
  _Float16* dst = w1img + (size_t)b * 16384;
  const int n = tid;
#pragma unroll
  for (int i = 0; i < 8; ++i) {
    const int g = i ^ (n & 7);
    f16x8 h;
#pragma unroll
    for (int j = 0; j < 8; ++j) h[j] = sT[(g * 8 + j) * 256 + n];
    *(f16x8*)(dst + (size_t)n * 64 + i * 8) = h;
  }
}

// ---------------------------------------------------------------------------
// gemm1 256x256 (bid < 512) + W2 image (bid >= 512, 1024-thr tile body).
// gemm1: BM=256 x BN=256 x BK=64, 1024 thr (16 waves 4M x 4N, wave 64x64,
// acc[4][4] proven register shape -> ~64 VGPR, cap 128, no spill).
// A = one native 256-row xg tile; B = one native 256-col w1img tile.
// LDS 64 KB single-buffer; 512 blocks = 2 exact rounds. bid&7=e XCD pin.
// Staged bytes 512 MB (-33% vs R15), barrier drains 8K (-50%).
// Epilogue: proven LDS-bounce, time-shared 8 slots x 2 phases.
// ---------------------------------------------------------------------------
__global__ __launch_bounds__(1024, 4) void gemm1_w2(
    const _Float16* __restrict__ xg, const _Float16* __restrict__ w1img,
    const float* __restrict__ b1, _Float16* __restrict__ hidden,
    const float* __restrict__ W2, _Float16* __restrict__ w2img)
{
  __shared__ _Float16 SH[32768];    // 64 KB: As = [256][64], Bs = [256][64]
  _Float16* As = SH;
  _Float16* Bs = SH + 16384;
  const int tid = threadIdx.x;
  const int bid = blockIdx.x;

  if (bid >= 512) {
    // ---- W2 image block (proven tile body, 1024-thr indexing) ----
    const int b = bid - 512;                    // 0..4095
    const int kt = b & 63, nt = (b >> 6) & 7, e = b >> 9;
    const float* src = W2 + (size_t)e * FF * DIM + (size_t)(kt * 64) * DIM + nt * 128;
    _Float16* sT = As;                          // [64][128] bounce (16 KB)
#pragma unroll
    for (int i = 0; i < 2; ++i) {
      const int q = i * 1024 + tid;             // 0..2047
      const int row = q >> 5, c4 = (q & 31) * 4;
      f32x4 u = *(const f32x4*)(src + (size_t)row * DIM + c4);
      f16x4 h;
#pragma unroll
      for (int c = 0; c < 4; ++c) h[c] = (_Float16)u[c];
      *(f16x4*)&sT[row * 128 + c4] = h;
    }
    __syncthreads();
    _Float16* dst = w2img + (size_t)b * 8192;
    const int n = tid & 127, gpos = tid >> 7;   // gpos 0..7
    const int g = gpos ^ (n & 7);
    f16x8 h;
#pragma unroll
    for (int j = 0; j < 8; ++j) h[j] = sT[(g * 8 + j) * 128 + n];
    *(f16x8*)(dst + (size_t)n * 64 + gpos * 8) = h;
    return;
  }

  // ---- gemm1 block: 256 rows x 256 cols ----
  const int lane = tid & 63, w = tid >> 6;      // w 0..15
  const int wm = w >> 2, wn = w & 3;            // 4M x 4N, wave = 64x64
  const int l15 = lane & 15, l4 = lane >> 4;
  const int e  = bid & 7;                       // expert -> XCD pin
  const int s  = bid >> 3;                      // 0..63
  const int mt = s & 3;                         // 256-row xg tile (4)
  const int nt = s >> 2;                        // 256-col F tile (16)

  const _Float16* aSrc = xg + (size_t)((e * 4 + mt) * 16) * 16384;
  const _Float16* bSrc = w1img + (size_t)(e * 256 + nt * 16) * 16384;

  f32x4 acc[4][4];
#pragma unroll
  for (int i = 0; i < 4; ++i)
#pragma unroll
    for (int j = 0; j < 4; ++j) acc[i][j] = (f32x4){0.f, 0.f, 0.f, 0.f};

  for (int kt = 0; kt < 16; ++kt) {
    __syncthreads();
#pragma unroll
    for (int i = 0; i < 2; ++i)
      cp16(&As[(i * 1024 + tid) * 8], aSrc + (size_t)kt * 16384 + (i * 1024 + tid) * 8);
#pragma unroll
    for (int i = 0; i < 2; ++i)
      cp16(&Bs[(i * 1024 + tid) * 8], bSrc + (size_t)kt * 16384 + (i * 1024 + tid) * 8);
    __syncthreads();
#pragma unroll
    for (int ks = 0; ks < 2; ++ks) {
      const int gq = ks * 4 + l4;
      f16x8 af[4], bf[4];
#pragma unroll
      for (int fm = 0; fm < 4; ++fm) {
        const int m = wm * 64 + fm * 16 + l15;                 // 0..255
        af[fm] = *(const f16x8*)&As[m * 64 + (gq ^ (m & 7)) * 8];
      }
#pragma unroll
      for (int fn = 0; fn < 4; ++fn) {
        const int n = wn * 64 + fn * 16 + l15;                 // 0..255
        bf[fn] = *(const f16x8*)&Bs[n * 64 + (gq ^ (n & 7)) * 8];
      }
#pragma unroll
      for (int fm = 0; fm < 4; ++fm)
#pragma unroll
        for (int fn = 0; fn < 4; ++fn)
          acc[fm][fn] = __builtin_amdgcn_mfma_f32_16x16x32_f16(af[fm], bf[fn], acc[fm][fn], 0, 0, 0);
    }
  }

  // ---- epilogue: LDS-bounce transpose (proven), 8 slots, 2 phases ----
  const int ftile = nt * 4 + wn;                // 0..63 (64-col chunk of FF)
  const int mt128 = mt * 2 + (wm >> 1);         // 0..7 (128-row image tile)
  const size_t tbase = ((size_t)((e * 8 + mt128) * 64) + ftile) * 8192;
  const int fbase = nt * 256 + wn * 64;
  __syncthreads();                              // K-loop LDS reads done
  for (int phase = 0; phase < 2; ++phase) {
    if ((w >> 3) == phase) {
      float* sw = (float*)SH + (size_t)(w & 7) * 1088;   // 4.25 KB slot
#pragma unroll
      for (int fm = 0; fm < 4; ++fm) {
#pragma unroll
        for (int fn = 0; fn < 4; ++fn) {
          const int floc = fn * 16 + l15;
          const float bb = b1[e * FF + fbase + floc];
          f32x4 v;
#pragma unroll
          for (int r = 0; r < 4; ++r) v[r] = fmaxf(acc[fm][fn][r] + bb, 0.f);
          *(f32x4*)&sw[floc * 17 + l4 * 4] = v;
        }
        const int p = l15;
        const int mrow = (wm & 1) * 64 + fm * 16 + p;    // row in 128-tile
#pragma unroll
        for (int it = 0; it < 2; ++it) {
          const int g = it * 4 + l4;
          f16x8 h;
#pragma unroll
          for (int j = 0; j < 8; ++j) h[j] = (_Float16)sw[(g * 8 + j) * 17 + p];
          *(f16x8*)&hidden[tbase + (size_t)mrow * 64 + (g ^ (mrow & 7)) * 8] = h;
        }
      }
    }
    __syncthreads();
  }
}

// ---------------------------------------------------------------------------
// GEMM2 (round-13/15 proven, dbuf): out[tok] = (hidden @ W2img + b2) * topw.
// 128x128xBK64, 512 thr (8 waves 4Mx2N), 2x32KB dbuf, 2 blocks/CU.
// bid = e + 8*(nt*8 + mt): expert pinned to XCD.
// ---------------------------------------------------------------------------
__global__ __launch_bounds__(512, 4) void gemm2_big(
    const _Float16* __restrict__ hidden, const _Float16* __restrict__ w2img,
    const float* __restrict__ b2, const int* __restrict__ idx,
    const float* __restrict__ topw, float* __restrict__ out)
{
  __shared__ _Float16 As[2][8192];
  __shared__ _Float16 Bs[2][8192];
  const int tid = threadIdx.x, lane = tid & 63, w = tid >> 6;
  const int wm = w >> 1, wn = w & 1;
  const int l15 = lane & 15, l4 = lane >> 4;
  const int bid = blockIdx.x;
  const int e  = bid & 7;
  const int s  = bid >> 3;       // 0..63
  const int nt = s >> 3;         // 0..7
  const int mt = s & 7;          // 0..7

  const _Float16* aSrc = hidden + ((size_t)((e * 8 + mt) * 64)) * 8192 + w * 1024 + lane * 8;
  const _Float16* bSrc = w2img  + ((size_t)((e * 8 + nt) * 64)) * 8192 + w * 1024 + lane * 8;

  f32x4 acc[2][4];
#pragma unroll
  for (int i = 0; i < 2; ++i)
#pragma unroll
    for (int j = 0; j < 4; ++j) acc[i][j] = (f32x4){0.f, 0.f, 0.f, 0.f};

#pragma unroll
  for (int i = 0; i < 2; ++i) {
    cp16(&As[0][w * 1024 + i * 512], aSrc + i * 512);
    cp16(&Bs[0][w * 1024 + i * 512], bSrc + i * 512);
  }
  __syncthreads();

  for (int kt = 0; kt < 64; ++kt) {
    const int cur = kt & 1;
    if (kt < 63) {
#pragma unroll
      for (int i = 0; i < 2; ++i) {
        cp16(&As[cur ^ 1][w * 1024 + i * 512], aSrc + (size_t)(kt + 1) * 8192 + i * 512);
        cp16(&Bs[cur ^ 1][w * 1024 + i * 512], bSrc + (size_t)(kt + 1) * 8192 + i * 512);
      }
    }
#pragma unroll
    for (int ks = 0; ks < 2; ++ks) {
      const int gq = ks * 4 + l4;
      f16x8 af[2], bf[4];
#pragma unroll
      for (int fm = 0; fm < 2; ++fm) {
        const int m = wm * 32 + fm * 16 + l15;
        af[fm] = *(const f16x8*)&As[cur][m * 64 + (gq ^ (m & 7)) * 8];
      }
#pragma unroll
      for (int fn = 0; fn < 4; ++fn) {
        const int n = wn * 64 + fn * 16 + l15;
        bf[fn] = *(const f16x8*)&Bs[cur][n * 64 + (gq ^ (n & 7)) * 8];
      }
#pragma unroll
      for (int fm = 0; fm < 2; ++fm)
#pragma unroll
        for (int fn = 0; fn < 4; ++fn)
          acc[fm][fn] = __builtin_amdgcn_mfma_f32_16x16x32_f16(af[fm], bf[fn], acc[fm][fn], 0, 0, 0);
    }
    __syncthreads();
  }

  int   toks[2][4];
  float wgts[2][4];
#pragma unroll
  for (int fm = 0; fm < 2; ++fm)
#pragma unroll
    for (int r = 0; r < 4; ++r) {
      const int row = mt * 128 + wm * 32 + fm * 16 + l4 * 4 + r;
      const int tk = idx[e * CAP + row];
      toks[fm][r] = tk;
      wgts[fm][r] = (tk < T_TOK) ? topw[tk] : 0.f;
    }
#pragma unroll
  for (int fn = 0; fn < 4; ++fn) {
    const int dcol = nt * 128 + wn * 64 + fn * 16 + l15;
    const float bb = b2[e * DIM + dcol];
#pragma unroll
    for (int fm = 0; fm < 2; ++fm)
#pragma unroll
      for (int r = 0; r < 4; ++r) {
        const int tk = toks[fm][r];
        if (tk < T_TOK)
          out[(size_t)tk * DIM + dcol] = (acc[fm][fn][r] + bb) * wgts[fm][r];
      }
  }
}

// ---------------------------------------------------------------------------
extern "C" void kernel_launch(void* const* d_in, const int* in_sizes, int n_in,
                              void* d_out, int out_size, void* d_ws, size_t ws_size,
                              hipStream_t stream)
{
  const float* x  = (const float*)d_in[0];
  const float* Wr = (const float*)d_in[1];
  const float* W1 = (const float*)d_in[2];
  const float* b1 = (const float*)d_in[3];
  const float* W2 = (const float*)d_in[4];
  const float* b2 = (const float*)d_in[5];
  float* out = (float*)d_out;
  char* ws = (char*)d_ws;

  const size_t HID  = 67108864ull;  // hidden image fp16
  const size_t WIMG = 67108864ull;  // W1 image
  const size_t XG   = 16777216ull;  // gathered-x image fp16

  _Float16* hidden = (_Float16*)ws;
  _Float16* w1img  = (_Float16*)(ws + HID);
  _Float16* xg     = (_Float16*)(ws + HID + WIMG);
  int*   idx  = (int*)(ws + HID + WIMG + XG);
  int*   top  = idx + 8192;
  float* topw = (float*)(top + 8192);
  _Float16* w2img = (_Float16*)(ws + HID + WIMG + XG + 3 * 32768ull);

  hipMemsetAsync(d_out, 0, (size_t)T_TOK * DIM * sizeof(float), stream);
  moe_router<<<T_TOK / 16, 256, 0, stream>>>(x, Wr, top, topw);
  moe_scan<<<1, 1024, 0, stream>>>(top, idx);
  xg_w1<<<512 + 2048, 256, 0, stream>>>(x, idx, xg, W1, w1img);
  gemm1_w2<<<512 + 4096, 1024, 0, stream>>>(xg, w1img, b1, hidden, W2, w2img);
  gemm2_big<<<NE * 8 * 8, 512, 0, stream>>>(hidden, w2img, b2, idx, topw, out);
}

// Round 17
// 310.184 us; speedup vs baseline: 1.0043x; 1.0043x over previous
//
#include <hip/hip_runtime.h>
#include <hip/hip_bf16.h>
#include <hip/hip_fp16.h>

typedef _Float16 f16x8 __attribute__((ext_vector_type(8)));
typedef _Float16 f16x4 __attribute__((ext_vector_type(4)));
typedef float f32x4 __attribute__((ext_vector_type(4)));

#define T_TOK 8192
#define DIM   1024
#define FF    4096
#define NE    8
#define CAP   1024

// ---------------------------------------------------------------------------
// async global->LDS 16B copy. LDS dest = wave-uniform base + lane*16 (HW);
// global src is per-lane.
// ---------------------------------------------------------------------------
__device__ __forceinline__ void cp16(_Float16* lds, const _Float16* g) {
  __builtin_amdgcn_global_load_lds(
      (const __attribute__((address_space(1))) unsigned int*)(const void*)g,
      (__attribute__((address_space(3))) unsigned int*)(void*)lds, 16, 0, 0);
}

// ---------------------------------------------------------------------------
// Router (proven)
// ---------------------------------------------------------------------------
__global__ __launch_bounds__(256) void moe_router(
    const float* __restrict__ x, const float* __restrict__ Wr,
    int* __restrict__ top, float* __restrict__ topw)
{
  __shared__ float sWr[DIM * 9];
  const int tid = threadIdx.x;
  for (int i = tid; i < DIM * NE; i += 256) {
    int d = i >> 3, e = i & 7;
    sWr[d * 9 + e] = Wr[i];
  }
  __syncthreads();
  const int lane = tid & 63, w = tid >> 6;
  for (int t = 0; t < 4; ++t) {
    const int token = blockIdx.x * 16 + w * 4 + t;
    float acc[8] = {0.f, 0.f, 0.f, 0.f, 0.f, 0.f, 0.f, 0.f};
    for (int j = 0; j < 16; ++j) {
      float xv = x[(size_t)token * DIM + j * 64 + lane];
      const float* wr = &sWr[(j * 64 + lane) * 9];
#pragma unroll
      for (int e = 0; e < 8; ++e) acc[e] += xv * wr[e];
    }
#pragma unroll
    for (int e = 0; e < 8; ++e) {
#pragma unroll
      for (int off = 32; off > 0; off >>= 1)
        acc[e] += __shfl_xor(acc[e], off, 64);
    }
    if (lane == 0) {
      float m = acc[0];
#pragma unroll
      for (int e = 1; e < 8; ++e) m = fmaxf(m, acc[e]);
      float s = 0.f;
#pragma unroll
      for (int e = 0; e < 8; ++e) s += expf(acc[e] - m);
      int bi = 0; float bv = acc[0];
#pragma unroll
      for (int e = 1; e < 8; ++e) { if (acc[e] > bv) { bv = acc[e]; bi = e; } }
      top[token]  = bi;
      topw[token] = 1.0f / s;
    }
  }
}

// ---------------------------------------------------------------------------
// Order-preserving dispatch (proven, 1024 thr)
// ---------------------------------------------------------------------------
__global__ __launch_bounds__(1024) void moe_scan(
    const int* __restrict__ top, int* __restrict__ idx)
{
  __shared__ int running[8];
  __shared__ int wcnt[16][8];
  __shared__ int wpre[16][8];
  __shared__ int cbase[8];
  const int tid = threadIdx.x, lane = tid & 63, w = tid >> 6;
  for (int i = tid; i < NE * CAP; i += 1024) idx[i] = T_TOK;
  if (tid < 8) running[tid] = 0;
  __syncthreads();
  for (int chunk = 0; chunk < T_TOK / 1024; ++chunk) {
    const int tok = chunk * 1024 + tid;
    const int e = top[tok];
    unsigned long long mymask = 0ull;
#pragma unroll
    for (int ee = 0; ee < 8; ++ee) {
      unsigned long long m = __ballot(e == ee);
      if (ee == e) mymask = m;
      if (lane == ee) wcnt[w][ee] = __builtin_popcountll(m);
    }
    const int rankw = __builtin_popcountll(mymask & ((1ull << lane) - 1ull));
    __syncthreads();
    if (tid < 8) {
      int s = 0;
#pragma unroll
      for (int ww = 0; ww < 16; ++ww) { wpre[ww][tid] = s; s += wcnt[ww][tid]; }
      cbase[tid] = running[tid];
      running[tid] += s;
    }
    __syncthreads();
    const int rank = cbase[e] + wpre[w][e] + rankw;
    if (rank < CAP) idx[e * CAP + rank] = tok;
  }
}

// ---------------------------------------------------------------------------
// Fused BW pass: xg image (bid < 512) + W1 image (512..2559) + W2 image
// (2560..6655). All pure-BW blocks, 32 KB LDS max -> dense near-peak wave.
// W2 conversion only needs to precede gemm2 (it does not depend on gemm1).
// ---------------------------------------------------------------------------
__global__ __launch_bounds__(256) void xg_w1_w2(
    const float* __restrict__ x, const int* __restrict__ idx,
    _Float16* __restrict__ xgimg,
    const float* __restrict__ W1, _Float16* __restrict__ w1img,
    const float* __restrict__ W2, _Float16* __restrict__ w2img)
{
  __shared__ _Float16 sT[64 * 256];   // 32 KB
  const int tid = threadIdx.x, bid = blockIdx.x;
  if (bid < 512) {
    // ---- xg block (proven body) ----
    const int kt = bid & 15, mt = (bid >> 4) & 3, e = bid >> 6;
    const int tok = idx[e * CAP + mt * 256 + tid];
    _Float16* dst = xgimg + (size_t)((e * 4 + mt) * 16 + kt) * 16384 + (size_t)tid * 64;
    if (tok < T_TOK) {
      const f32x4* src = (const f32x4*)(x + (size_t)tok * DIM + kt * 64);
      f32x4 v[16];
#pragma unroll
      for (int i = 0; i < 16; ++i) v[i] = src[i];
#pragma unroll
      for (int g = 0; g < 8; ++g) {
        f16x8 h;
#pragma unroll
        for (int c = 0; c < 4; ++c) {
          h[c]     = (_Float16)v[2 * g][c];
          h[4 + c] = (_Float16)v[2 * g + 1][c];
        }
        *(f16x8*)(dst + ((g ^ (tid & 7)) * 8)) = h;
      }
    } else {
      f16x8 z = {};
#pragma unroll
      for (int g = 0; g < 8; ++g) *(f16x8*)(dst + g * 8) = z;
    }
    return;
  }
  if (bid < 2560) {
    // ---- W1 image block (proven body): tile b = e*256 + nt*16 + kt ----
    const int b = bid - 512;                    // 0..2047
    const int kt = b & 15, nt = (b >> 4) & 15, e = b >> 8;
    const float* src = W1 + (size_t)e * DIM * FF + (size_t)(kt * 64) * FF + nt * 256;
#pragma unroll
    for (int i = 0; i < 16; ++i) {
      const int q = i * 256 + tid;
      const int row = q >> 6, c4 = (q & 63) * 4;
      f32x4 u = *(const f32x4*)(src + (size_t)row * FF + c4);
      f16x4 h;
#pragma unroll
      for (int c = 0; c < 4; ++c) h[c] = (_Float16)u[c];
      *(f16x4*)&sT[row * 256 + c4] = h;
    }
    __syncthreads();
    _Float16* dst = w1img + (size_t)b * 16384;
    const int n = tid;
#pragma unroll
    for (int i = 0; i < 8; ++i) {
      const int g = i ^ (n & 7);
      f16x8 h;
#pragma unroll
      for (int j = 0; j < 8; ++j) h[j] = sT[(g * 8 + j) * 256 + n];
      *(f16x8*)(dst + (size_t)n * 64 + i * 8) = h;
    }
    return;
  }
  // ---- W2 image block (round-8 proven body): tile b = e*512 + nt*64 + kt ----
  const int b = bid - 2560;                     // 0..4095
  const int kt = b & 63, nt = (b >> 6) & 7, e = b >> 9;
  const float* src = W2 + (size_t)e * FF * DIM + (size_t)(kt * 64) * DIM + nt * 128;
#pragma unroll
  for (int i = 0; i < 8; ++i) {
    const int q = i * 256 + tid;
    const int row = q >> 5, c4 = (q & 31) * 4;
    f32x4 u = *(const f32x4*)(src + (size_t)row * DIM + c4);
    f16x4 h;
#pragma unroll
    for (int c = 0; c < 4; ++c) h[c] = (_Float16)u[c];
    *(f16x4*)&sT[row * 128 + c4] = h;
  }
  __syncthreads();
  _Float16* dst = w2img + (size_t)b * 8192;
  const int n = tid & 127, gb = (tid >> 7) * 4;
#pragma unroll
  for (int i = 0; i < 4; ++i) {
    const int gpos = gb + i, g = gpos ^ (n & 7);
    f16x8 h;
#pragma unroll
    for (int j = 0; j < 8; ++j) h[j] = sT[(g * 8 + j) * 128 + n];
    *(f16x8*)(dst + (size_t)n * 64 + gpos * 8) = h;
  }
}

// ---------------------------------------------------------------------------
// GEMM1 (round-15 proven, best): BM=128 x BN=256 x BK=64, 512 thr (8 waves
// 2M x 4N, wave 64x64, acc[4][4]), 48 KB LDS single-buffer, 2 blocks/CU,
// 1024 blocks = 2 exact rounds. B-tile = one native w1img 256-col tile.
// bid&7 = e pins each expert to one XCD.
// ---------------------------------------------------------------------------
__global__ __launch_bounds__(512, 4) void gemm1_big(
    const _Float16* __restrict__ xg, const _Float16* __restrict__ w1img,
    const float* __restrict__ b1, _Float16* __restrict__ hidden)
{
  __shared__ _Float16 SH[24576];    // 48 KB: As = SH[0..8191], Bs = SH[8192..]
  _Float16* As = SH;
  _Float16* Bs = SH + 8192;
  const int tid = threadIdx.x;
  const int bid = blockIdx.x;

  const int lane = tid & 63, w = tid >> 6;
  const int wm = w >> 2, wn = w & 3;            // 2M x 4N, wave = 64x64
  const int l15 = lane & 15, l4 = lane >> 4;
  const int e  = bid & 7;                       // expert -> XCD pin
  const int s  = bid >> 3;                      // 0..127
  const int mt = s & 7;                         // 128-row tile (8)
  const int nt = s >> 3;                        // 256-col F tile (16)

  const _Float16* aSrc = xg + ((size_t)(e * 4 + (mt >> 1)) * 16) * 16384
                         + (size_t)(mt & 1) * 8192;
  const _Float16* bSrc = w1img + (size_t)(e * 256 + nt * 16) * 16384;

  f32x4 acc[4][4];
#pragma unroll
  for (int i = 0; i < 4; ++i)
#pragma unroll
    for (int j = 0; j < 4; ++j) acc[i][j] = (f32x4){0.f, 0.f, 0.f, 0.f};

  for (int kt = 0; kt < 16; ++kt) {
    __syncthreads();
#pragma unroll
    for (int i = 0; i < 2; ++i)
      cp16(&As[(i * 512 + tid) * 8], aSrc + (size_t)kt * 16384 + (i * 512 + tid) * 8);
#pragma unroll
    for (int i = 0; i < 4; ++i)
      cp16(&Bs[(i * 512 + tid) * 8], bSrc + (size_t)kt * 16384 + (i * 512 + tid) * 8);
    __syncthreads();
#pragma unroll
    for (int ks = 0; ks < 2; ++ks) {
      const int gq = ks * 4 + l4;
      f16x8 af[4], bf[4];
#pragma unroll
      for (int fm = 0; fm < 4; ++fm) {
        const int m = wm * 64 + fm * 16 + l15;                 // 0..127
        af[fm] = *(const f16x8*)&As[m * 64 + (gq ^ (m & 7)) * 8];
      }
#pragma unroll
      for (int fn = 0; fn < 4; ++fn) {
        const int n = wn * 64 + fn * 16 + l15;                 // 0..255
        bf[fn] = *(const f16x8*)&Bs[n * 64 + (gq ^ (n & 7)) * 8];
      }
#pragma unroll
      for (int fm = 0; fm < 4; ++fm)
#pragma unroll
        for (int fn = 0; fn < 4; ++fn)
          acc[fm][fn] = __builtin_amdgcn_mfma_f32_16x16x32_f16(af[fm], bf[fn], acc[fm][fn], 0, 0, 0);
    }
  }

  // ---- epilogue: LDS-bounce transpose, relu(acc+b1) -> hidden image ----
  __syncthreads();
  float* sw = (float*)SH + (size_t)w * 1088;    // 4.25 KB scratch per wave
  const int ftile = nt * 4 + wn;                // 0..63
  const size_t tbase = ((size_t)((e * 8 + mt) * 64) + ftile) * 8192;
  const int fbase = nt * 256 + wn * 64;
#pragma unroll
  for (int fm = 0; fm < 4; ++fm) {
#pragma unroll
    for (int fn = 0; fn < 4; ++fn) {
      const int floc = fn * 16 + l15;
      const float bb = b1[e * FF + fbase + floc];
      f32x4 v;
#pragma unroll
      for (int r = 0; r < 4; ++r) v[r] = fmaxf(acc[fm][fn][r] + bb, 0.f);
      *(f32x4*)&sw[floc * 17 + l4 * 4] = v;
    }
    const int p = l15;
    const int mrow = wm * 64 + fm * 16 + p;     // 0..127 within image tile
#pragma unroll
    for (int it = 0; it < 2; ++it) {
      const int g = it * 4 + l4;
      f16x8 h;
#pragma unroll
      for (int j = 0; j < 8; ++j) h[j] = (_Float16)sw[(g * 8 + j) * 17 + p];
      *(f16x8*)&hidden[tbase + (size_t)mrow * 64 + (g ^ (mrow & 7)) * 8] = h;
    }
  }
}

// ---------------------------------------------------------------------------
// GEMM2 (round-13/15 proven, dbuf): out[tok] = (hidden @ W2img + b2) * topw.
// 128x128xBK64, 512 thr (8 waves 4Mx2N), 2x32KB dbuf, 2 blocks/CU.
// bid = e + 8*(nt*8 + mt): expert pinned to XCD.
// ---------------------------------------------------------------------------
__global__ __launch_bounds__(512, 4) void gemm2_big(
    const _Float16* __restrict__ hidden, const _Float16* __restrict__ w2img,
    const float* __restrict__ b2, const int* __restrict__ idx,
    const float* __restrict__ topw, float* __restrict__ out)
{
  __shared__ _Float16 As[2][8192];
  __shared__ _Float16 Bs[2][8192];
  const int tid = threadIdx.x, lane = tid & 63, w = tid >> 6;
  const int wm = w >> 1, wn = w & 1;
  const int l15 = lane & 15, l4 = lane >> 4;
  const int bid = blockIdx.x;
  const int e  = bid & 7;
  const int s  = bid >> 3;       // 0..63
  const int nt = s >> 3;         // 0..7
  const int mt = s & 7;          // 0..7

  const _Float16* aSrc = hidden + ((size_t)((e * 8 + mt) * 64)) * 8192 + w * 1024 + lane * 8;
  const _Float16* bSrc = w2img  + ((size_t)((e * 8 + nt) * 64)) * 8192 + w * 1024 + lane * 8;

  f32x4 acc[2][4];
#pragma unroll
  for (int i = 0; i < 2; ++i)
#pragma unroll
    for (int j = 0; j < 4; ++j) acc[i][j] = (f32x4){0.f, 0.f, 0.f, 0.f};

#pragma unroll
  for (int i = 0; i < 2; ++i) {
    cp16(&As[0][w * 1024 + i * 512], aSrc + i * 512);
    cp16(&Bs[0][w * 1024 + i * 512], bSrc + i * 512);
  }
  __syncthreads();

  for (int kt = 0; kt < 64; ++kt) {
    const int cur = kt & 1;
    if (kt < 63) {
#pragma unroll
      for (int i = 0; i < 2; ++i) {
        cp16(&As[cur ^ 1][w * 1024 + i * 512], aSrc + (size_t)(kt + 1) * 8192 + i * 512);
        cp16(&Bs[cur ^ 1][w * 1024 + i * 512], bSrc + (size_t)(kt + 1) * 8192 + i * 512);
      }
    }
#pragma unroll
    for (int ks = 0; ks < 2; ++ks) {
      const int gq = ks * 4 + l4;
      f16x8 af[2], bf[4];
#pragma unroll
      for (int fm = 0; fm < 2; ++fm) {
        const int m = wm * 32 + fm * 16 + l15;
        af[fm] = *(const f16x8*)&As[cur][m * 64 + (gq ^ (m & 7)) * 8];
      }
#pragma unroll
      for (int fn = 0; fn < 4; ++fn) {
        const int n = wn * 64 + fn * 16 + l15;
        bf[fn] = *(const f16x8*)&Bs[cur][n * 64 + (gq ^ (n & 7)) * 8];
      }
#pragma unroll
      for (int fm = 0; fm < 2; ++fm)
#pragma unroll
        for (int fn = 0; fn < 4; ++fn)
          acc[fm][fn] = __builtin_amdgcn_mfma_f32_16x16x32_f16(af[fm], bf[fn], acc[fm][fn], 0, 0, 0);
    }
    __syncthreads();
  }

  int   toks[2][4];
  float wgts[2][4];
#pragma unroll
  for (int fm = 0; fm < 2; ++fm)
#pragma unroll
    for (int r = 0; r < 4; ++r) {
      const int row = mt * 128 + wm * 32 + fm * 16 + l4 * 4 + r;
      const int tk = idx[e * CAP + row];
      toks[fm][r] = tk;
      wgts[fm][r] = (tk < T_TOK) ? topw[tk] : 0.f;
    }
#pragma unroll
  for (int fn = 0; fn < 4; ++fn) {
    const int dcol = nt * 128 + wn * 64 + fn * 16 + l15;
    const float bb = b2[e * DIM + dcol];
#pragma unroll
    for (int fm = 0; fm < 2; ++fm)
#pragma unroll
      for (int r = 0; r < 4; ++r) {
        const int tk = toks[fm][r];
        if (tk < T_TOK)
          out[(size_t)tk * DIM + dcol] = (acc[fm][fn][r] + bb) * wgts[fm][r];
      }
  }
}

// ---------------------------------------------------------------------------
extern "C" void kernel_launch(void* const* d_in, const int* in_sizes, int n_in,
                              void* d_out, int out_size, void* d_ws, size_t ws_size,
                              hipStream_t stream)
{
  const float* x  = (const float*)d_in[0];
  const float* Wr = (const float*)d_in[1];
  const float* W1 = (const float*)d_in[2];
  const float* b1 = (const float*)d_in[3];
  const float* W2 = (const float*)d_in[4];
  const float* b2 = (const float*)d_in[5];
  float* out = (float*)d_out;
  char* ws = (char*)d_ws;

  const size_t HID  = 67108864ull;  // hidden image fp16
  const size_t WIMG = 67108864ull;  // W1 image
  const size_t XG   = 16777216ull;  // gathered-x image fp16

  _Float16* hidden = (_Float16*)ws;
  _Float16* w1img  = (_Float16*)(ws + HID);
  _Float16* xg     = (_Float16*)(ws + HID + WIMG);
  int*   idx  = (int*)(ws + HID + WIMG + XG);
  int*   top  = idx + 8192;
  float* topw = (float*)(top + 8192);
  _Float16* w2img = (_Float16*)(ws + HID + WIMG + XG + 3 * 32768ull);

  hipMemsetAsync(d_out, 0, (size_t)T_TOK * DIM * sizeof(float), stream);
  moe_router<<<T_TOK / 16, 256, 0, stream>>>(x, Wr, top, topw);
  moe_scan<<<1, 1024, 0, stream>>>(top, idx);
  xg_w1_w2<<<512 + 2048 + 4096, 256, 0, stream>>>(x, idx, xg, W1, w1img, W2, w2img);
  gemm1_big<<<1024, 512, 0, stream>>>(xg, w1img, b1, hidden);
  gemm2_big<<<NE * 8 * 8, 512, 0, stream>>>(hidden, w2img, b2, idx, topw, out);
}

// Round 18
// 299.008 us; speedup vs baseline: 1.0418x; 1.0374x over previous
//
#include <hip/hip_runtime.h>
#include <hip/hip_bf16.h>
#include <hip/hip_fp16.h>

typedef _Float16 f16x8 __attribute__((ext_vector_type(8)));
typedef _Float16 f16x4 __attribute__((ext_vector_type(4)));
typedef float f32x4 __attribute__((ext_vector_type(4)));

#define T_TOK 8192
#define DIM   1024
#define FF    4096
#define NE    8
#define CAP   1024

// ---------------------------------------------------------------------------
// async global->LDS 16B copy. LDS dest = wave-uniform base + lane*16 (HW);
// global src is per-lane.
// ---------------------------------------------------------------------------
__device__ __forceinline__ void cp16(_Float16* lds, const _Float16* g) {
  __builtin_amdgcn_global_load_lds(
      (const __attribute__((address_space(1))) unsigned int*)(const void*)g,
      (__attribute__((address_space(3))) unsigned int*)(void*)lds, 16, 0, 0);
}

// ---------------------------------------------------------------------------
// Router (proven)
// ---------------------------------------------------------------------------
__global__ __launch_bounds__(256) void moe_router(
    const float* __restrict__ x, const float* __restrict__ Wr,
    int* __restrict__ top, float* __restrict__ topw)
{
  __shared__ float sWr[DIM * 9];
  const int tid = threadIdx.x;
  for (int i = tid; i < DIM * NE; i += 256) {
    int d = i >> 3, e = i & 7;
    sWr[d * 9 + e] = Wr[i];
  }
  __syncthreads();
  const int lane = tid & 63, w = tid >> 6;
  for (int t = 0; t < 4; ++t) {
    const int token = blockIdx.x * 16 + w * 4 + t;
    float acc[8] = {0.f, 0.f, 0.f, 0.f, 0.f, 0.f, 0.f, 0.f};
    for (int j = 0; j < 16; ++j) {
      float xv = x[(size_t)token * DIM + j * 64 + lane];
      const float* wr = &sWr[(j * 64 + lane) * 9];
#pragma unroll
      for (int e = 0; e < 8; ++e) acc[e] += xv * wr[e];
    }
#pragma unroll
    for (int e = 0; e < 8; ++e) {
#pragma unroll
      for (int off = 32; off > 0; off >>= 1)
        acc[e] += __shfl_xor(acc[e], off, 64);
    }
    if (lane == 0) {
      float m = acc[0];
#pragma unroll
      for (int e = 1; e < 8; ++e) m = fmaxf(m, acc[e]);
      float s = 0.f;
#pragma unroll
      for (int e = 0; e < 8; ++e) s += expf(acc[e] - m);
      int bi = 0; float bv = acc[0];
#pragma unroll
      for (int e = 1; e < 8; ++e) { if (acc[e] > bv) { bv = acc[e]; bi = e; } }
      top[token]  = bi;
      topw[token] = 1.0f / s;
    }
  }
}

// ---------------------------------------------------------------------------
// Order-preserving dispatch (proven, 1024 thr)
// ---------------------------------------------------------------------------
__global__ __launch_bounds__(1024) void moe_scan(
    const int* __restrict__ top, int* __restrict__ idx)
{
  __shared__ int running[8];
  __shared__ int wcnt[16][8];
  __shared__ int wpre[16][8];
  __shared__ int cbase[8];
  const int tid = threadIdx.x, lane = tid & 63, w = tid >> 6;
  for (int i = tid; i < NE * CAP; i += 1024) idx[i] = T_TOK;
  if (tid < 8) running[tid] = 0;
  __syncthreads();
  for (int chunk = 0; chunk < T_TOK / 1024; ++chunk) {
    const int tok = chunk * 1024 + tid;
    const int e = top[tok];
    unsigned long long mymask = 0ull;
#pragma unroll
    for (int ee = 0; ee < 8; ++ee) {
      unsigned long long m = __ballot(e == ee);
      if (ee == e) mymask = m;
      if (lane == ee) wcnt[w][ee] = __builtin_popcountll(m);
    }
    const int rankw = __builtin_popcountll(mymask & ((1ull << lane) - 1ull));
    __syncthreads();
    if (tid < 8) {
      int s = 0;
#pragma unroll
      for (int ww = 0; ww < 16; ++ww) { wpre[ww][tid] = s; s += wcnt[ww][tid]; }
      cbase[tid] = running[tid];
      running[tid] += s;
    }
    __syncthreads();
    const int rank = cbase[e] + wpre[w][e] + rankw;
    if (rank < CAP) idx[e * CAP + rank] = tok;
  }
}

// ---------------------------------------------------------------------------
// Fused: xg image (bid < 512) + W1 image (bid >= 512). (proven)
// ---------------------------------------------------------------------------
__global__ __launch_bounds__(256) void xg_w1(
    const float* __restrict__ x, const int* __restrict__ idx,
    _Float16* __restrict__ xgimg,
    const float* __restrict__ W1, _Float16* __restrict__ w1img)
{
  __shared__ _Float16 sT[64 * 256];   // 32 KB (W1 path)
  const int tid = threadIdx.x, bid = blockIdx.x;
  if (bid < 512) {
    const int kt = bid & 15, mt = (bid >> 4) & 3, e = bid >> 6;
    const int tok = idx[e * CAP + mt * 256 + tid];
    _Float16* dst = xgimg + (size_t)((e * 4 + mt) * 16 + kt) * 16384 + (size_t)tid * 64;
    if (tok < T_TOK) {
      const f32x4* src = (const f32x4*)(x + (size_t)tok * DIM + kt * 64);
      f32x4 v[16];
#pragma unroll
      for (int i = 0; i < 16; ++i) v[i] = src[i];
#pragma unroll
      for (int g = 0; g < 8; ++g) {
        f16x8 h;
#pragma unroll
        for (int c = 0; c < 4; ++c) {
          h[c]     = (_Float16)v[2 * g][c];
          h[4 + c] = (_Float16)v[2 * g + 1][c];
        }
        *(f16x8*)(dst + ((g ^ (tid & 7)) * 8)) = h;
      }
    } else {
      f16x8 z = {};
#pragma unroll
      for (int g = 0; g < 8; ++g) *(f16x8*)(dst + g * 8) = z;
    }
    return;
  }
  const int b = bid - 512;                      // 0..2047
  const int kt = b & 15, nt = (b >> 4) & 15, e = b >> 8;
  const float* src = W1 + (size_t)e * DIM * FF + (size_t)(kt * 64) * FF + nt * 256;
#pragma unroll
  for (int i = 0; i < 16; ++i) {
    const int q = i * 256 + tid;
    const int row = q >> 6, c4 = (q & 63) * 4;
    f32x4 u = *(const f32x4*)(src + (size_t)row * FF + c4);
    f16x4 h;
#pragma unroll
    for (int c = 0; c < 4; ++c) h[c] = (_Float16)u[c];
    *(f16x4*)&sT[row * 256 + c4] = h;
  }
  __syncthreads();
  _Float16* dst = w1img + (size_t)b * 16384;
  const int n = tid;
#pragma unroll
  for (int i = 0; i < 8; ++i) {
    const int g = i ^ (n & 7);
    f16x8 h;
#pragma unroll
    for (int j = 0; j < 8; ++j) h[j] = sT[(g * 8 + j) * 256 + n];
    *(f16x8*)(dst + (size_t)n * 64 + i * 8) = h;
  }
}

// ---------------------------------------------------------------------------
// gemm1 128x256 (bid < 1024) + W2 image (bid >= 1024, 512-thr proven body).
// gemm1: BM=128 x BN=256 x BK=64, 512 thr (8 waves 2M x 4N, wave 64x64,
// acc[4][4] proven shape), 48 KB LDS single-buffer, launch_bounds(512,4)
// -> 2 blocks/CU, 1024 blocks = 2 exact rounds. B-tile = one native w1img
// 256-col image tile. Staged bytes/output -25% vs 128x128; 64 MFMA/K-step.
// bid&7 = e pins each expert to one XCD (proven pattern).
// ---------------------------------------------------------------------------
__global__ __launch_bounds__(512, 4) void gemm1_w2(
    const _Float16* __restrict__ xg, const _Float16* __restrict__ w1img,
    const float* __restrict__ b1, _Float16* __restrict__ hidden,
    const float* __restrict__ W2, _Float16* __restrict__ w2img)
{
  __shared__ _Float16 SH[24576];    // 48 KB: As = SH[0..8191], Bs = SH[8192..]
  _Float16* As = SH;
  _Float16* Bs = SH + 8192;
  const int tid = threadIdx.x;
  const int bid = blockIdx.x;

  if (bid >= 1024) {
    // ---- W2 image block (round-12 proven 512-thr body) ----
    const int b = bid - 1024;                   // 0..4095
    const int kt = b & 63, nt = (b >> 6) & 7, e = b >> 9;
    const float* src = W2 + (size_t)e * FF * DIM + (size_t)(kt * 64) * DIM + nt * 128;
    _Float16* sT = As;                          // [64][128] bounce (16 KB)
#pragma unroll
    for (int i = 0; i < 4; ++i) {
      const int q = i * 512 + tid;
      const int row = q >> 5, c4 = (q & 31) * 4;
      f32x4 u = *(const f32x4*)(src + (size_t)row * DIM + c4);
      f16x4 h;
#pragma unroll
      for (int c = 0; c < 4; ++c) h[c] = (_Float16)u[c];
      *(f16x4*)&sT[row * 128 + c4] = h;
    }
    __syncthreads();
    _Float16* dst = w2img + (size_t)b * 8192;
    const int n = tid & 127, gb = (tid >> 7) * 2;
#pragma unroll
    for (int i = 0; i < 2; ++i) {
      const int gpos = gb + i, g = gpos ^ (n & 7);
      f16x8 h;
#pragma unroll
      for (int j = 0; j < 8; ++j) h[j] = sT[(g * 8 + j) * 128 + n];
      *(f16x8*)(dst + (size_t)n * 64 + gpos * 8) = h;
    }
    return;
  }

  // ---- gemm1 block: 128 rows x 256 cols ----
  const int lane = tid & 63, w = tid >> 6;
  const int wm = w >> 2, wn = w & 3;            // 2M x 4N, wave = 64x64
  const int l15 = lane & 15, l4 = lane >> 4;
  const int e  = bid & 7;                       // expert -> XCD pin
  const int s  = bid >> 3;                      // 0..127
  const int mt = s & 7;                         // 128-row tile (8)
  const int nt = s >> 3;                        // 256-col F tile (16)

  // A = 128-row half of one native xg 256-row tile; B = one w1img 256-tile
  const _Float16* aSrc = xg + ((size_t)(e * 4 + (mt >> 1)) * 16) * 16384
                         + (size_t)(mt & 1) * 8192;
  const _Float16* bSrc = w1img + (size_t)(e * 256 + nt * 16) * 16384;

  f32x4 acc[4][4];
#pragma unroll
  for (int i = 0; i < 4; ++i)
#pragma unroll
    for (int j = 0; j < 4; ++j) acc[i][j] = (f32x4){0.f, 0.f, 0.f, 0.f};

  for (int kt = 0; kt < 16; ++kt) {
    __syncthreads();
#pragma unroll
    for (int i = 0; i < 2; ++i)
      cp16(&As[(i * 512 + tid) * 8], aSrc + (size_t)kt * 16384 + (i * 512 + tid) * 8);
#pragma unroll
    for (int i = 0; i < 4; ++i)
      cp16(&Bs[(i * 512 + tid) * 8], bSrc + (size_t)kt * 16384 + (i * 512 + tid) * 8);
    __syncthreads();
#pragma unroll
    for (int ks = 0; ks < 2; ++ks) {
      const int gq = ks * 4 + l4;
      f16x8 af[4], bf[4];
#pragma unroll
      for (int fm = 0; fm < 4; ++fm) {
        const int m = wm * 64 + fm * 16 + l15;                 // 0..127
        af[fm] = *(const f16x8*)&As[m * 64 + (gq ^ (m & 7)) * 8];
      }
#pragma unroll
      for (int fn = 0; fn < 4; ++fn) {
        const int n = wn * 64 + fn * 16 + l15;                 // 0..255
        bf[fn] = *(const f16x8*)&Bs[n * 64 + (gq ^ (n & 7)) * 8];
      }
#pragma unroll
      for (int fm = 0; fm < 4; ++fm)
#pragma unroll
        for (int fn = 0; fn < 4; ++fn)
          acc[fm][fn] = __builtin_amdgcn_mfma_f32_16x16x32_f16(af[fm], bf[fn], acc[fm][fn], 0, 0, 0);
    }
  }

  // ---- epilogue: LDS-bounce transpose, relu(acc+b1) -> hidden image ----
  // (verbatim round-13 logic; wave owns 64-col ftile = nt*4 + wn)
  __syncthreads();
  float* sw = (float*)SH + (size_t)w * 1088;    // 4.25 KB scratch per wave
  const int ftile = nt * 4 + wn;                // 0..63
  const size_t tbase = ((size_t)((e * 8 + mt) * 64) + ftile) * 8192;
  const int fbase = nt * 256 + wn * 64;
#pragma unroll
  for (int fm = 0; fm < 4; ++fm) {
#pragma unroll
    for (int fn = 0; fn < 4; ++fn) {
      const int floc = fn * 16 + l15;
      const float bb = b1[e * FF + fbase + floc];
      f32x4 v;
#pragma unroll
      for (int r = 0; r < 4; ++r) v[r] = fmaxf(acc[fm][fn][r] + bb, 0.f);
      *(f32x4*)&sw[floc * 17 + l4 * 4] = v;
    }
    const int p = l15;
    const int mrow = wm * 64 + fm * 16 + p;     // 0..127 within image tile
#pragma unroll
    for (int it = 0; it < 2; ++it) {
      const int g = it * 4 + l4;
      f16x8 h;
#pragma unroll
      for (int j = 0; j < 8; ++j) h[j] = (_Float16)sw[(g * 8 + j) * 17 + p];
      *(f16x8*)&hidden[tbase + (size_t)mrow * 64 + (g ^ (mrow & 7)) * 8] = h;
    }
  }
}

// ---------------------------------------------------------------------------
// GEMM2 (round-13 proven, dbuf): out[tok] = (hidden @ W2img + b2) * topw.
// 128x128xBK64, 512 thr (8 waves 4Mx2N), 2x32KB dbuf, 2 blocks/CU.
// bid = e + 8*(nt*8 + mt): expert pinned to XCD.
// ---------------------------------------------------------------------------
__global__ __launch_bounds__(512, 4) void gemm2_big(
    const _Float16* __restrict__ hidden, const _Float16* __restrict__ w2img,
    const float* __restrict__ b2, const int* __restrict__ idx,
    const float* __restrict__ topw, float* __restrict__ out)
{
  __shared__ _Float16 As[2][8192];
  __shared__ _Float16 Bs[2][8192];
  const int tid = threadIdx.x, lane = tid & 63, w = tid >> 6;
  const int wm = w >> 1, wn = w & 1;
  const int l15 = lane & 15, l4 = lane >> 4;
  const int bid = blockIdx.x;
  const int e  = bid & 7;
  const int s  = bid >> 3;       // 0..63
  const int nt = s >> 3;         // 0..7
  const int mt = s & 7;          // 0..7

  const _Float16* aSrc = hidden + ((size_t)((e * 8 + mt) * 64)) * 8192 + w * 1024 + lane * 8;
  const _Float16* bSrc = w2img  + ((size_t)((e * 8 + nt) * 64)) * 8192 + w * 1024 + lane * 8;

  f32x4 acc[2][4];
#pragma unroll
  for (int i = 0; i < 2; ++i)
#pragma unroll
    for (int j = 0; j < 4; ++j) acc[i][j] = (f32x4){0.f, 0.f, 0.f, 0.f};

#pragma unroll
  for (int i = 0; i < 2; ++i) {
    cp16(&As[0][w * 1024 + i * 512], aSrc + i * 512);
    cp16(&Bs[0][w * 1024 + i * 512], bSrc + i * 512);
  }
  __syncthreads();

  for (int kt = 0; kt < 64; ++kt) {
    const int cur = kt & 1;
    if (kt < 63) {
#pragma unroll
      for (int i = 0; i < 2; ++i) {
        cp16(&As[cur ^ 1][w * 1024 + i * 512], aSrc + (size_t)(kt + 1) * 8192 + i * 512);
        cp16(&Bs[cur ^ 1][w * 1024 + i * 512], bSrc + (size_t)(kt + 1) * 8192 + i * 512);
      }
    }
#pragma unroll
    for (int ks = 0; ks < 2; ++ks) {
      const int gq = ks * 4 + l4;
      f16x8 af[2], bf[4];
#pragma unroll
      for (int fm = 0; fm < 2; ++fm) {
        const int m = wm * 32 + fm * 16 + l15;
        af[fm] = *(const f16x8*)&As[cur][m * 64 + (gq ^ (m & 7)) * 8];
      }
#pragma unroll
      for (int fn = 0; fn < 4; ++fn) {
        const int n = wn * 64 + fn * 16 + l15;
        bf[fn] = *(const f16x8*)&Bs[cur][n * 64 + (gq ^ (n & 7)) * 8];
      }
#pragma unroll
      for (int fm = 0; fm < 2; ++fm)
#pragma unroll
        for (int fn = 0; fn < 4; ++fn)
          acc[fm][fn] = __builtin_amdgcn_mfma_f32_16x16x32_f16(af[fm], bf[fn], acc[fm][fn], 0, 0, 0);
    }
    __syncthreads();
  }

  int   toks[2][4];
  float wgts[2][4];
#pragma unroll
  for (int fm = 0; fm < 2; ++fm)
#pragma unroll
    for (int r = 0; r < 4; ++r) {
      const int row = mt * 128 + wm * 32 + fm * 16 + l4 * 4 + r;
      const int tk = idx[e * CAP + row];
      toks[fm][r] = tk;
      wgts[fm][r] = (tk < T_TOK) ? topw[tk] : 0.f;
    }
#pragma unroll
  for (int fn = 0; fn < 4; ++fn) {
    const int dcol = nt * 128 + wn * 64 + fn * 16 + l15;
    const float bb = b2[e * DIM + dcol];
#pragma unroll
    for (int fm = 0; fm < 2; ++fm)
#pragma unroll
      for (int r = 0; r < 4; ++r) {
        const int tk = toks[fm][r];
        if (tk < T_TOK)
          out[(size_t)tk * DIM + dcol] = (acc[fm][fn][r] + bb) * wgts[fm][r];
      }
  }
}

// ---------------------------------------------------------------------------
extern "C" void kernel_launch(void* const* d_in, const int* in_sizes, int n_in,
                              void* d_out, int out_size, void* d_ws, size_t ws_size,
                              hipStream_t stream)
{
  const float* x  = (const float*)d_in[0];
  const float* Wr = (const float*)d_in[1];
  const float* W1 = (const float*)d_in[2];
  const float* b1 = (const float*)d_in[3];
  const float* W2 = (const float*)d_in[4];
  const float* b2 = (const float*)d_in[5];
  float* out = (float*)d_out;
  char* ws = (char*)d_ws;

  const size_t HID  = 67108864ull;  // hidden image fp16
  const size_t WIMG = 67108864ull;  // W1 image
  const size_t XG   = 16777216ull;  // gathered-x image fp16

  _Float16* hidden = (_Float16*)ws;
  _Float16* w1img  = (_Float16*)(ws + HID);
  _Float16* xg     = (_Float16*)(ws + HID + WIMG);
  int*   idx  = (int*)(ws + HID + WIMG + XG);
  int*   top  = idx + 8192;
  float* topw = (float*)(top + 8192);
  _Float16* w2img = (_Float16*)(ws + HID + WIMG + XG + 3 * 32768ull);

  hipMemsetAsync(d_out, 0, (size_t)T_TOK * DIM * sizeof(float), stream);
  moe_router<<<T_TOK / 16, 256, 0, stream>>>(x, Wr, top, topw);
  moe_scan<<<1, 1024, 0, stream>>>(top, idx);
  xg_w1<<<512 + 2048, 256, 0, stream>>>(x, idx, xg, W1, w1img);
  gemm1_w2<<<1024 + 4096, 512, 0, stream>>>(xg, w1img, b1, hidden, W2, w2img);
  gemm2_big<<<NE * 8 * 8, 512, 0, stream>>>(hidden, w2img, b2, idx, topw, out);
}

// Round 19
// 291.678 us; speedup vs baseline: 1.0680x; 1.0251x over previous
//
#include <hip/hip_runtime.h>
#include <hip/hip_bf16.h>
#include <hip/hip_fp16.h>

typedef _Float16 f16x8 __attribute__((ext_vector_type(8)));
typedef _Float16 f16x4 __attribute__((ext_vector_type(4)));
typedef float f32x4 __attribute__((ext_vector_type(4)));

#define T_TOK 8192
#define DIM   1024
#define FF    4096
#define NE    8
#define CAP   1024

// ---------------------------------------------------------------------------
// async global->LDS 16B copy. LDS dest = wave-uniform base + lane*16 (HW);
// global src is per-lane.
// ---------------------------------------------------------------------------
__device__ __forceinline__ void cp16(_Float16* lds, const _Float16* g) {
  __builtin_amdgcn_global_load_lds(
      (const __attribute__((address_space(1))) unsigned int*)(const void*)g,
      (__attribute__((address_space(3))) unsigned int*)(void*)lds, 16, 0, 0);
}

// ---------------------------------------------------------------------------
// Router (proven)
// ---------------------------------------------------------------------------
__global__ __launch_bounds__(256) void moe_router(
    const float* __restrict__ x, const float* __restrict__ Wr,
    int* __restrict__ top, float* __restrict__ topw)
{
  __shared__ float sWr[DIM * 9];
  const int tid = threadIdx.x;
  for (int i = tid; i < DIM * NE; i += 256) {
    int d = i >> 3, e = i & 7;
    sWr[d * 9 + e] = Wr[i];
  }
  __syncthreads();
  const int lane = tid & 63, w = tid >> 6;
  for (int t = 0; t < 4; ++t) {
    const int token = blockIdx.x * 16 + w * 4 + t;
    float acc[8] = {0.f, 0.f, 0.f, 0.f, 0.f, 0.f, 0.f, 0.f};
    for (int j = 0; j < 16; ++j) {
      float xv = x[(size_t)token * DIM + j * 64 + lane];
      const float* wr = &sWr[(j * 64 + lane) * 9];
#pragma unroll
      for (int e = 0; e < 8; ++e) acc[e] += xv * wr[e];
    }
#pragma unroll
    for (int e = 0; e < 8; ++e) {
#pragma unroll
      for (int off = 32; off > 0; off >>= 1)
        acc[e] += __shfl_xor(acc[e], off, 64);
    }
    if (lane == 0) {
      float m = acc[0];
#pragma unroll
      for (int e = 1; e < 8; ++e) m = fmaxf(m, acc[e]);
      float s = 0.f;
#pragma unroll
      for (int e = 0; e < 8; ++e) s += expf(acc[e] - m);
      int bi = 0; float bv = acc[0];
#pragma unroll
      for (int e = 1; e < 8; ++e) { if (acc[e] > bv) { bv = acc[e]; bi = e; } }
      top[token]  = bi;
      topw[token] = 1.0f / s;
    }
  }
}

// ---------------------------------------------------------------------------
// Order-preserving dispatch (proven, 1024 thr)
// ---------------------------------------------------------------------------
__global__ __launch_bounds__(1024) void moe_scan(
    const int* __restrict__ top, int* __restrict__ idx)
{
  __shared__ int running[8];
  __shared__ int wcnt[16][8];
  __shared__ int wpre[16][8];
  __shared__ int cbase[8];
  const int tid = threadIdx.x, lane = tid & 63, w = tid >> 6;
  for (int i = tid; i < NE * CAP; i += 1024) idx[i] = T_TOK;
  if (tid < 8) running[tid] = 0;
  __syncthreads();
  for (int chunk = 0; chunk < T_TOK / 1024; ++chunk) {
    const int tok = chunk * 1024 + tid;
    const int e = top[tok];
    unsigned long long mymask = 0ull;
#pragma unroll
    for (int ee = 0; ee < 8; ++ee) {
      unsigned long long m = __ballot(e == ee);
      if (ee == e) mymask = m;
      if (lane == ee) wcnt[w][ee] = __builtin_popcountll(m);
    }
    const int rankw = __builtin_popcountll(mymask & ((1ull << lane) - 1ull));
    __syncthreads();
    if (tid < 8) {
      int s = 0;
#pragma unroll
      for (int ww = 0; ww < 16; ++ww) { wpre[ww][tid] = s; s += wcnt[ww][tid]; }
      cbase[tid] = running[tid];
      running[tid] += s;
    }
    __syncthreads();
    const int rank = cbase[e] + wpre[w][e] + rankw;
    if (rank < CAP) idx[e * CAP + rank] = tok;
  }
}

// ---------------------------------------------------------------------------
// Fused: xg image (bid < 512) + W1 image (bid >= 512). (proven)
// ---------------------------------------------------------------------------
__global__ __launch_bounds__(256) void xg_w1(
    const float* __restrict__ x, const int* __restrict__ idx,
    _Float16* __restrict__ xgimg,
    const float* __restrict__ W1, _Float16* __restrict__ w1img)
{
  __shared__ _Float16 sT[64 * 256];   // 32 KB (W1 path)
  const int tid = threadIdx.x, bid = blockIdx.x;
  if (bid < 512) {
    const int kt = bid & 15, mt = (bid >> 4) & 3, e = bid >> 6;
    const int tok = idx[e * CAP + mt * 256 + tid];
    _Float16* dst = xgimg + (size_t)((e * 4 + mt) * 16 + kt) * 16384 + (size_t)tid * 64;
    if (tok < T_TOK) {
      const f32x4* src = (const f32x4*)(x + (size_t)tok * DIM + kt * 64);
      f32x4 v[16];
#pragma unroll
      for (int i = 0; i < 16; ++i) v[i] = src[i];
#pragma unroll
      for (int g = 0; g < 8; ++g) {
        f16x8 h;
#pragma unroll
        for (int c = 0; c < 4; ++c) {
          h[c]     = (_Float16)v[2 * g][c];
          h[4 + c] = (_Float16)v[2 * g + 1][c];
        }
        *(f16x8*)(dst + ((g ^ (tid & 7)) * 8)) = h;
      }
    } else {
      f16x8 z = {};
#pragma unroll
      for (int g = 0; g < 8; ++g) *(f16x8*)(dst + g * 8) = z;
    }
    return;
  }
  const int b = bid - 512;                      // 0..2047
  const int kt = b & 15, nt = (b >> 4) & 15, e = b >> 8;
  const float* src = W1 + (size_t)e * DIM * FF + (size_t)(kt * 64) * FF + nt * 256;
#pragma unroll
  for (int i = 0; i < 16; ++i) {
    const int q = i * 256 + tid;
    const int row = q >> 6, c4 = (q & 63) * 4;
    f32x4 u = *(const f32x4*)(src + (size_t)row * FF + c4);
    f16x4 h;
#pragma unroll
    for (int c = 0; c < 4; ++c) h[c] = (_Float16)u[c];
    *(f16x4*)&sT[row * 256 + c4] = h;
  }
  __syncthreads();
  _Float16* dst = w1img + (size_t)b * 16384;
  const int n = tid;
#pragma unroll
  for (int i = 0; i < 8; ++i) {
    const int g = i ^ (n & 7);
    f16x8 h;
#pragma unroll
    for (int j = 0; j < 8; ++j) h[j] = sT[(g * 8 + j) * 256 + n];
    *(f16x8*)(dst + (size_t)n * 64 + i * 8) = h;
  }
}

// ---------------------------------------------------------------------------
// gemm1 128x256 (bid < 1024) + W2 image (bid >= 1024, 512-thr proven body).
// (verbatim round-15 best)
// ---------------------------------------------------------------------------
__global__ __launch_bounds__(512, 4) void gemm1_w2(
    const _Float16* __restrict__ xg, const _Float16* __restrict__ w1img,
    const float* __restrict__ b1, _Float16* __restrict__ hidden,
    const float* __restrict__ W2, _Float16* __restrict__ w2img)
{
  __shared__ _Float16 SH[24576];    // 48 KB: As = SH[0..8191], Bs = SH[8192..]
  _Float16* As = SH;
  _Float16* Bs = SH + 8192;
  const int tid = threadIdx.x;
  const int bid = blockIdx.x;

  if (bid >= 1024) {
    // ---- W2 image block (round-12 proven 512-thr body) ----
    const int b = bid - 1024;                   // 0..4095
    const int kt = b & 63, nt = (b >> 6) & 7, e = b >> 9;
    const float* src = W2 + (size_t)e * FF * DIM + (size_t)(kt * 64) * DIM + nt * 128;
    _Float16* sT = As;                          // [64][128] bounce (16 KB)
#pragma unroll
    for (int i = 0; i < 4; ++i) {
      const int q = i * 512 + tid;
      const int row = q >> 5, c4 = (q & 31) * 4;
      f32x4 u = *(const f32x4*)(src + (size_t)row * DIM + c4);
      f16x4 h;
#pragma unroll
      for (int c = 0; c < 4; ++c) h[c] = (_Float16)u[c];
      *(f16x4*)&sT[row * 128 + c4] = h;
    }
    __syncthreads();
    _Float16* dst = w2img + (size_t)b * 8192;
    const int n = tid & 127, gb = (tid >> 7) * 2;
#pragma unroll
    for (int i = 0; i < 2; ++i) {
      const int gpos = gb + i, g = gpos ^ (n & 7);
      f16x8 h;
#pragma unroll
      for (int j = 0; j < 8; ++j) h[j] = sT[(g * 8 + j) * 128 + n];
      *(f16x8*)(dst + (size_t)n * 64 + gpos * 8) = h;
    }
    return;
  }

  // ---- gemm1 block: 128 rows x 256 cols ----
  const int lane = tid & 63, w = tid >> 6;
  const int wm = w >> 2, wn = w & 3;            // 2M x 4N, wave = 64x64
  const int l15 = lane & 15, l4 = lane >> 4;
  const int e  = bid & 7;                       // expert -> XCD pin
  const int s  = bid >> 3;                      // 0..127
  const int mt = s & 7;                         // 128-row tile (8)
  const int nt = s >> 3;                        // 256-col F tile (16)

  const _Float16* aSrc = xg + ((size_t)(e * 4 + (mt >> 1)) * 16) * 16384
                         + (size_t)(mt & 1) * 8192;
  const _Float16* bSrc = w1img + (size_t)(e * 256 + nt * 16) * 16384;

  f32x4 acc[4][4];
#pragma unroll
  for (int i = 0; i < 4; ++i)
#pragma unroll
    for (int j = 0; j < 4; ++j) acc[i][j] = (f32x4){0.f, 0.f, 0.f, 0.f};

  for (int kt = 0; kt < 16; ++kt) {
    __syncthreads();
#pragma unroll
    for (int i = 0; i < 2; ++i)
      cp16(&As[(i * 512 + tid) * 8], aSrc + (size_t)kt * 16384 + (i * 512 + tid) * 8);
#pragma unroll
    for (int i = 0; i < 4; ++i)
      cp16(&Bs[(i * 512 + tid) * 8], bSrc + (size_t)kt * 16384 + (i * 512 + tid) * 8);
    __syncthreads();
#pragma unroll
    for (int ks = 0; ks < 2; ++ks) {
      const int gq = ks * 4 + l4;
      f16x8 af[4], bf[4];
#pragma unroll
      for (int fm = 0; fm < 4; ++fm) {
        const int m = wm * 64 + fm * 16 + l15;                 // 0..127
        af[fm] = *(const f16x8*)&As[m * 64 + (gq ^ (m & 7)) * 8];
      }
#pragma unroll
      for (int fn = 0; fn < 4; ++fn) {
        const int n = wn * 64 + fn * 16 + l15;                 // 0..255
        bf[fn] = *(const f16x8*)&Bs[n * 64 + (gq ^ (n & 7)) * 8];
      }
#pragma unroll
      for (int fm = 0; fm < 4; ++fm)
#pragma unroll
        for (int fn = 0; fn < 4; ++fn)
          acc[fm][fn] = __builtin_amdgcn_mfma_f32_16x16x32_f16(af[fm], bf[fn], acc[fm][fn], 0, 0, 0);
    }
  }

  // ---- epilogue: LDS-bounce transpose, relu(acc+b1) -> hidden image ----
  __syncthreads();
  float* sw = (float*)SH + (size_t)w * 1088;    // 4.25 KB scratch per wave
  const int ftile = nt * 4 + wn;                // 0..63
  const size_t tbase = ((size_t)((e * 8 + mt) * 64) + ftile) * 8192;
  const int fbase = nt * 256 + wn * 64;
#pragma unroll
  for (int fm = 0; fm < 4; ++fm) {
#pragma unroll
    for (int fn = 0; fn < 4; ++fn) {
      const int floc = fn * 16 + l15;
      const float bb = b1[e * FF + fbase + floc];
      f32x4 v;
#pragma unroll
      for (int r = 0; r < 4; ++r) v[r] = fmaxf(acc[fm][fn][r] + bb, 0.f);
      *(f32x4*)&sw[floc * 17 + l4 * 4] = v;
    }
    const int p = l15;
    const int mrow = wm * 64 + fm * 16 + p;     // 0..127 within image tile
#pragma unroll
    for (int it = 0; it < 2; ++it) {
      const int g = it * 4 + l4;
      f16x8 h;
#pragma unroll
      for (int j = 0; j < 8; ++j) h[j] = (_Float16)sw[(g * 8 + j) * 17 + p];
      *(f16x8*)&hidden[tbase + (size_t)mrow * 64 + (g ^ (mrow & 7)) * 8] = h;
    }
  }
}

// ---------------------------------------------------------------------------
// GEMM2 BK=128: out[tok] = (hidden @ W2img + b2) * topw. 128x128xBK128,
// 512 thr (8 waves 4Mx2N, acc[2][4]), 64 KB single-buffer (two 64-k halves),
// 2 blocks/CU. Halves barrier-drain count (64 -> 32) at identical staged
// bytes; 32 MFMA between barrier pairs. K-halves are adjacent image subtiles
// -> staging stays pure-linear cp16. bid = e + 8*s: expert pinned to XCD.
// ---------------------------------------------------------------------------
__global__ __launch_bounds__(512, 4) void gemm2_big(
    const _Float16* __restrict__ hidden, const _Float16* __restrict__ w2img,
    const float* __restrict__ b2, const int* __restrict__ idx,
    const float* __restrict__ topw, float* __restrict__ out)
{
  __shared__ _Float16 As[2][8192];   // [k-half][128 rows][64 k] = 32 KB
  __shared__ _Float16 Bs[2][8192];   // [k-half][128 n][64 k]    = 32 KB
  const int tid = threadIdx.x, lane = tid & 63, w = tid >> 6;
  const int wm = w >> 1, wn = w & 1;
  const int l15 = lane & 15, l4 = lane >> 4;
  const int bid = blockIdx.x;
  const int e  = bid & 7;
  const int s  = bid >> 3;       // 0..63
  const int nt = s >> 3;         // 0..7
  const int mt = s & 7;          // 0..7

  const _Float16* aSrc = hidden + ((size_t)((e * 8 + mt) * 64)) * 8192;
  const _Float16* bSrc = w2img  + ((size_t)((e * 8 + nt) * 64)) * 8192;

  f32x4 acc[2][4];
#pragma unroll
  for (int i = 0; i < 2; ++i)
#pragma unroll
    for (int j = 0; j < 4; ++j) acc[i][j] = (f32x4){0.f, 0.f, 0.f, 0.f};

  for (int kt = 0; kt < 32; ++kt) {
    __syncthreads();
#pragma unroll
    for (int h = 0; h < 2; ++h) {
      const size_t ko = (size_t)(2 * kt + h) * 8192;
#pragma unroll
      for (int i = 0; i < 2; ++i) {
        cp16(&As[h][(i * 512 + tid) * 8], aSrc + ko + (i * 512 + tid) * 8);
        cp16(&Bs[h][(i * 512 + tid) * 8], bSrc + ko + (i * 512 + tid) * 8);
      }
    }
    __syncthreads();
#pragma unroll
    for (int ks = 0; ks < 4; ++ks) {
      const int h  = ks >> 1;
      const int gq = (ks & 1) * 4 + l4;
      f16x8 af[2], bf[4];
#pragma unroll
      for (int fm = 0; fm < 2; ++fm) {
        const int m = wm * 32 + fm * 16 + l15;
        af[fm] = *(const f16x8*)&As[h][m * 64 + (gq ^ (m & 7)) * 8];
      }
#pragma unroll
      for (int fn = 0; fn < 4; ++fn) {
        const int n = wn * 64 + fn * 16 + l15;
        bf[fn] = *(const f16x8*)&Bs[h][n * 64 + (gq ^ (n & 7)) * 8];
      }
#pragma unroll
      for (int fm = 0; fm < 2; ++fm)
#pragma unroll
        for (int fn = 0; fn < 4; ++fn)
          acc[fm][fn] = __builtin_amdgcn_mfma_f32_16x16x32_f16(af[fm], bf[fn], acc[fm][fn], 0, 0, 0);
    }
  }

  // epilogue: scatter (acc + b2) * topw to token rows
  int   toks[2][4];
  float wgts[2][4];
#pragma unroll
  for (int fm = 0; fm < 2; ++fm)
#pragma unroll
    for (int r = 0; r < 4; ++r) {
      const int row = mt * 128 + wm * 32 + fm * 16 + l4 * 4 + r;
      const int tk = idx[e * CAP + row];
      toks[fm][r] = tk;
      wgts[fm][r] = (tk < T_TOK) ? topw[tk] : 0.f;
    }
#pragma unroll
  for (int fn = 0; fn < 4; ++fn) {
    const int dcol = nt * 128 + wn * 64 + fn * 16 + l15;
    const float bb = b2[e * DIM + dcol];
#pragma unroll
    for (int fm = 0; fm < 2; ++fm)
#pragma unroll
      for (int r = 0; r < 4; ++r) {
        const int tk = toks[fm][r];
        if (tk < T_TOK)
          out[(size_t)tk * DIM + dcol] = (acc[fm][fn][r] + bb) * wgts[fm][r];
      }
  }
}

// ---------------------------------------------------------------------------
extern "C" void kernel_launch(void* const* d_in, const int* in_sizes, int n_in,
                              void* d_out, int out_size, void* d_ws, size_t ws_size,
                              hipStream_t stream)
{
  const float* x  = (const float*)d_in[0];
  const float* Wr = (const float*)d_in[1];
  const float* W1 = (const float*)d_in[2];
  const float* b1 = (const float*)d_in[3];
  const float* W2 = (const float*)d_in[4];
  const float* b2 = (const float*)d_in[5];
  float* out = (float*)d_out;
  char* ws = (char*)d_ws;

  const size_t HID  = 67108864ull;  // hidden image fp16
  const size_t WIMG = 67108864ull;  // W1 image
  const size_t XG   = 16777216ull;  // gathered-x image fp16

  _Float16* hidden = (_Float16*)ws;
  _Float16* w1img  = (_Float16*)(ws + HID);
  _Float16* xg     = (_Float16*)(ws + HID + WIMG);
  int*   idx  = (int*)(ws + HID + WIMG + XG);
  int*   top  = idx + 8192;
  float* topw = (float*)(top + 8192);
  _Float16* w2img = (_Float16*)(ws + HID + WIMG + XG + 3 * 32768ull);

  hipMemsetAsync(d_out, 0, (size_t)T_TOK * DIM * sizeof(float), stream);
  moe_router<<<T_TOK / 16, 256, 0, stream>>>(x, Wr, top, topw);
  moe_scan<<<1, 1024, 0, stream>>>(top, idx);
  xg_w1<<<512 + 2048, 256, 0, stream>>>(x, idx, xg, W1, w1img);
  gemm1_w2<<<1024 + 4096, 512, 0, stream>>>(xg, w1img, b1, hidden, W2, w2img);
  gemm2_big<<<NE * 8 * 8, 512, 0, stream>>>(hidden, w2img, b2, idx, topw, out);
}

// Round 20
// 286.100 us; speedup vs baseline: 1.0888x; 1.0195x over previous
//
#include <hip/hip_runtime.h>
#include <hip/hip_bf16.h>
#include <hip/hip_fp16.h>

typedef _Float16 f16x8 __attribute__((ext_vector_type(8)));
typedef _Float16 f16x4 __attribute__((ext_vector_type(4)));
typedef float f32x4 __attribute__((ext_vector_type(4)));

#define T_TOK 8192
#define DIM   1024
#define FF    4096
#define NE    8
#define CAP   1024

// ---------------------------------------------------------------------------
// async global->LDS 16B copy. LDS dest = wave-uniform base + lane*16 (HW);
// global src is per-lane.
// ---------------------------------------------------------------------------
__device__ __forceinline__ void cp16(_Float16* lds, const _Float16* g) {
  __builtin_amdgcn_global_load_lds(
      (const __attribute__((address_space(1))) unsigned int*)(const void*)g,
      (__attribute__((address_space(3))) unsigned int*)(void*)lds, 16, 0, 0);
}

// ---------------------------------------------------------------------------
// Router (proven)
// ---------------------------------------------------------------------------
__global__ __launch_bounds__(256) void moe_router(
    const float* __restrict__ x, const float* __restrict__ Wr,
    int* __restrict__ top, float* __restrict__ topw)
{
  __shared__ float sWr[DIM * 9];
  const int tid = threadIdx.x;
  for (int i = tid; i < DIM * NE; i += 256) {
    int d = i >> 3, e = i & 7;
    sWr[d * 9 + e] = Wr[i];
  }
  __syncthreads();
  const int lane = tid & 63, w = tid >> 6;
  for (int t = 0; t < 4; ++t) {
    const int token = blockIdx.x * 16 + w * 4 + t;
    float acc[8] = {0.f, 0.f, 0.f, 0.f, 0.f, 0.f, 0.f, 0.f};
    for (int j = 0; j < 16; ++j) {
      float xv = x[(size_t)token * DIM + j * 64 + lane];
      const float* wr = &sWr[(j * 64 + lane) * 9];
#pragma unroll
      for (int e = 0; e < 8; ++e) acc[e] += xv * wr[e];
    }
#pragma unroll
    for (int e = 0; e < 8; ++e) {
#pragma unroll
      for (int off = 32; off > 0; off >>= 1)
        acc[e] += __shfl_xor(acc[e], off, 64);
    }
    if (lane == 0) {
      float m = acc[0];
#pragma unroll
      for (int e = 1; e < 8; ++e) m = fmaxf(m, acc[e]);
      float s = 0.f;
#pragma unroll
      for (int e = 0; e < 8; ++e) s += expf(acc[e] - m);
      int bi = 0; float bv = acc[0];
#pragma unroll
      for (int e = 1; e < 8; ++e) { if (acc[e] > bv) { bv = acc[e]; bi = e; } }
      top[token]  = bi;
      topw[token] = 1.0f / s;
    }
  }
}

// ---------------------------------------------------------------------------
// Order-preserving dispatch (proven, 1024 thr) + dropped-token list.
// Tokens with rank >= CAP are recorded so zero_drops can zero exactly their
// out rows (replaces the 33.5 MB global memset).
// ---------------------------------------------------------------------------
__global__ __launch_bounds__(1024) void moe_scan(
    const int* __restrict__ top, int* __restrict__ idx,
    int* __restrict__ dropCnt, int* __restrict__ dropList)
{
  __shared__ int running[8];
  __shared__ int wcnt[16][8];
  __shared__ int wpre[16][8];
  __shared__ int cbase[8];
  const int tid = threadIdx.x, lane = tid & 63, w = tid >> 6;
  for (int i = tid; i < NE * CAP; i += 1024) idx[i] = T_TOK;
  if (tid < 8) running[tid] = 0;
  if (tid == 0) dropCnt[0] = 0;
  __syncthreads();
  for (int chunk = 0; chunk < T_TOK / 1024; ++chunk) {
    const int tok = chunk * 1024 + tid;
    const int e = top[tok];
    unsigned long long mymask = 0ull;
#pragma unroll
    for (int ee = 0; ee < 8; ++ee) {
      unsigned long long m = __ballot(e == ee);
      if (ee == e) mymask = m;
      if (lane == ee) wcnt[w][ee] = __builtin_popcountll(m);
    }
    const int rankw = __builtin_popcountll(mymask & ((1ull << lane) - 1ull));
    __syncthreads();
    if (tid < 8) {
      int s = 0;
#pragma unroll
      for (int ww = 0; ww < 16; ++ww) { wpre[ww][tid] = s; s += wcnt[ww][tid]; }
      cbase[tid] = running[tid];
      running[tid] += s;
    }
    __syncthreads();
    const int rank = cbase[e] + wpre[w][e] + rankw;
    if (rank < CAP) idx[e * CAP + rank] = tok;
    else { const int p = atomicAdd(dropCnt, 1); dropList[p] = tok; }
  }
}

// ---------------------------------------------------------------------------
// Zero only the dropped-token out rows (one row per block iteration;
// 256 thr x f32x4 = 1024 floats = one full row).
// ---------------------------------------------------------------------------
__global__ __launch_bounds__(256) void zero_drops(
    const int* __restrict__ dropCnt, const int* __restrict__ dropList,
    float* __restrict__ out)
{
  const int n = dropCnt[0];
  const f32x4 z = {0.f, 0.f, 0.f, 0.f};
  for (int i = blockIdx.x; i < n; i += gridDim.x) {
    const int tok = dropList[i];
    *(f32x4*)&out[(size_t)tok * DIM + threadIdx.x * 4] = z;
  }
}

// ---------------------------------------------------------------------------
// Fused: xg image (bid < 512) + W1 image (bid >= 512). (proven)
// ---------------------------------------------------------------------------
__global__ __launch_bounds__(256) void xg_w1(
    const float* __restrict__ x, const int* __restrict__ idx,
    _Float16* __restrict__ xgimg,
    const float* __restrict__ W1, _Float16* __restrict__ w1img)
{
  __shared__ _Float16 sT[64 * 256];   // 32 KB (W1 path)
  const int tid = threadIdx.x, bid = blockIdx.x;
  if (bid < 512) {
    const int kt = bid & 15, mt = (bid >> 4) & 3, e = bid >> 6;
    const int tok = idx[e * CAP + mt * 256 + tid];
    _Float16* dst = xgimg + (size_t)((e * 4 + mt) * 16 + kt) * 16384 + (size_t)tid * 64;
    if (tok < T_TOK) {
      const f32x4* src = (const f32x4*)(x + (size_t)tok * DIM + kt * 64);
      f32x4 v[16];
#pragma unroll
      for (int i = 0; i < 16; ++i) v[i] = src[i];
#pragma unroll
      for (int g = 0; g < 8; ++g) {
        f16x8 h;
#pragma unroll
        for (int c = 0; c < 4; ++c) {
          h[c]     = (_Float16)v[2 * g][c];
          h[4 + c] = (_Float16)v[2 * g + 1][c];
        }
        *(f16x8*)(dst + ((g ^ (tid & 7)) * 8)) = h;
      }
    } else {
      f16x8 z = {};
#pragma unroll
      for (int g = 0; g < 8; ++g) *(f16x8*)(dst + g * 8) = z;
    }
    return;
  }
  const int b = bid - 512;                      // 0..2047
  const int kt = b & 15, nt = (b >> 4) & 15, e = b >> 8;
  const float* src = W1 + (size_t)e * DIM * FF + (size_t)(kt * 64) * FF + nt * 256;
#pragma unroll
  for (int i = 0; i < 16; ++i) {
    const int q = i * 256 + tid;
    const int row = q >> 6, c4 = (q & 63) * 4;
    f32x4 u = *(const f32x4*)(src + (size_t)row * FF + c4);
    f16x4 h;
#pragma unroll
    for (int c = 0; c < 4; ++c) h[c] = (_Float16)u[c];
    *(f16x4*)&sT[row * 256 + c4] = h;
  }
  __syncthreads();
  _Float16* dst = w1img + (size_t)b * 16384;
  const int n = tid;
#pragma unroll
  for (int i = 0; i < 8; ++i) {
    const int g = i ^ (n & 7);
    f16x8 h;
#pragma unroll
    for (int j = 0; j < 8; ++j) h[j] = sT[(g * 8 + j) * 256 + n];
    *(f16x8*)(dst + (size_t)n * 64 + i * 8) = h;
  }
}

// ---------------------------------------------------------------------------
// gemm1 128x256 (bid < 1024) + W2 image (bid >= 1024, 512-thr proven body).
// (verbatim round-15/19 best)
// ---------------------------------------------------------------------------
__global__ __launch_bounds__(512, 4) void gemm1_w2(
    const _Float16* __restrict__ xg, const _Float16* __restrict__ w1img,
    const float* __restrict__ b1, _Float16* __restrict__ hidden,
    const float* __restrict__ W2, _Float16* __restrict__ w2img)
{
  __shared__ _Float16 SH[24576];    // 48 KB: As = SH[0..8191], Bs = SH[8192..]
  _Float16* As = SH;
  _Float16* Bs = SH + 8192;
  const int tid = threadIdx.x;
  const int bid = blockIdx.x;

  if (bid >= 1024) {
    // ---- W2 image block (round-12 proven 512-thr body) ----
    const int b = bid - 1024;                   // 0..4095
    const int kt = b & 63, nt = (b >> 6) & 7, e = b >> 9;
    const float* src = W2 + (size_t)e * FF * DIM + (size_t)(kt * 64) * DIM + nt * 128;
    _Float16* sT = As;                          // [64][128] bounce (16 KB)
#pragma unroll
    for (int i = 0; i < 4; ++i) {
      const int q = i * 512 + tid;
      const int row = q >> 5, c4 = (q & 31) * 4;
      f32x4 u = *(const f32x4*)(src + (size_t)row * DIM + c4);
      f16x4 h;
#pragma unroll
      for (int c = 0; c < 4; ++c) h[c] = (_Float16)u[c];
      *(f16x4*)&sT[row * 128 + c4] = h;
    }
    __syncthreads();
    _Float16* dst = w2img + (size_t)b * 8192;
    const int n = tid & 127, gb = (tid >> 7) * 2;
#pragma unroll
    for (int i = 0; i < 2; ++i) {
      const int gpos = gb + i, g = gpos ^ (n & 7);
      f16x8 h;
#pragma unroll
      for (int j = 0; j < 8; ++j) h[j] = sT[(g * 8 + j) * 128 + n];
      *(f16x8*)(dst + (size_t)n * 64 + gpos * 8) = h;
    }
    return;
  }

  // ---- gemm1 block: 128 rows x 256 cols ----
  const int lane = tid & 63, w = tid >> 6;
  const int wm = w >> 2, wn = w & 3;            // 2M x 4N, wave = 64x64
  const int l15 = lane & 15, l4 = lane >> 4;
  const int e  = bid & 7;                       // expert -> XCD pin
  const int s  = bid >> 3;                      // 0..127
  const int mt = s & 7;                         // 128-row tile (8)
  const int nt = s >> 3;                        // 256-col F tile (16)

  const _Float16* aSrc = xg + ((size_t)(e * 4 + (mt >> 1)) * 16) * 16384
                         + (size_t)(mt & 1) * 8192;
  const _Float16* bSrc = w1img + (size_t)(e * 256 + nt * 16) * 16384;

  f32x4 acc[4][4];
#pragma unroll
  for (int i = 0; i < 4; ++i)
#pragma unroll
    for (int j = 0; j < 4; ++j) acc[i][j] = (f32x4){0.f, 0.f, 0.f, 0.f};

  for (int kt = 0; kt < 16; ++kt) {
    __syncthreads();
#pragma unroll
    for (int i = 0; i < 2; ++i)
      cp16(&As[(i * 512 + tid) * 8], aSrc + (size_t)kt * 16384 + (i * 512 + tid) * 8);
#pragma unroll
    for (int i = 0; i < 4; ++i)
      cp16(&Bs[(i * 512 + tid) * 8], bSrc + (size_t)kt * 16384 + (i * 512 + tid) * 8);
    __syncthreads();
#pragma unroll
    for (int ks = 0; ks < 2; ++ks) {
      const int gq = ks * 4 + l4;
      f16x8 af[4], bf[4];
#pragma unroll
      for (int fm = 0; fm < 4; ++fm) {
        const int m = wm * 64 + fm * 16 + l15;                 // 0..127
        af[fm] = *(const f16x8*)&As[m * 64 + (gq ^ (m & 7)) * 8];
      }
#pragma unroll
      for (int fn = 0; fn < 4; ++fn) {
        const int n = wn * 64 + fn * 16 + l15;                 // 0..255
        bf[fn] = *(const f16x8*)&Bs[n * 64 + (gq ^ (n & 7)) * 8];
      }
#pragma unroll
      for (int fm = 0; fm < 4; ++fm)
#pragma unroll
        for (int fn = 0; fn < 4; ++fn)
          acc[fm][fn] = __builtin_amdgcn_mfma_f32_16x16x32_f16(af[fm], bf[fn], acc[fm][fn], 0, 0, 0);
    }
  }

  // ---- epilogue: LDS-bounce transpose, relu(acc+b1) -> hidden image ----
  __syncthreads();
  float* sw = (float*)SH + (size_t)w * 1088;    // 4.25 KB scratch per wave
  const int ftile = nt * 4 + wn;                // 0..63
  const size_t tbase = ((size_t)((e * 8 + mt) * 64) + ftile) * 8192;
  const int fbase = nt * 256 + wn * 64;
#pragma unroll
  for (int fm = 0; fm < 4; ++fm) {
#pragma unroll
    for (int fn = 0; fn < 4; ++fn) {
      const int floc = fn * 16 + l15;
      const float bb = b1[e * FF + fbase + floc];
      f32x4 v;
#pragma unroll
      for (int r = 0; r < 4; ++r) v[r] = fmaxf(acc[fm][fn][r] + bb, 0.f);
      *(f32x4*)&sw[floc * 17 + l4 * 4] = v;
    }
    const int p = l15;
    const int mrow = wm * 64 + fm * 16 + p;     // 0..127 within image tile
#pragma unroll
    for (int it = 0; it < 2; ++it) {
      const int g = it * 4 + l4;
      f16x8 h;
#pragma unroll
      for (int j = 0; j < 8; ++j) h[j] = (_Float16)sw[(g * 8 + j) * 17 + p];
      *(f16x8*)&hidden[tbase + (size_t)mrow * 64 + (g ^ (mrow & 7)) * 8] = h;
    }
  }
}

// ---------------------------------------------------------------------------
// GEMM2 BK=128 (round-19 proven): out[tok] = (hidden @ W2img + b2) * topw.
// 128x128xBK128, 512 thr (8 waves 4Mx2N, acc[2][4]), 64 KB single-buffer,
// 2 blocks/CU, 32 drains/block, 32 MFMA per barrier pair.
// bid = e + 8*s: expert pinned to XCD.
// ---------------------------------------------------------------------------
__global__ __launch_bounds__(512, 4) void gemm2_big(
    const _Float16* __restrict__ hidden, const _Float16* __restrict__ w2img,
    const float* __restrict__ b2, const int* __restrict__ idx,
    const float* __restrict__ topw, float* __restrict__ out)
{
  __shared__ _Float16 As[2][8192];   // [k-half][128 rows][64 k] = 32 KB
  __shared__ _Float16 Bs[2][8192];   // [k-half][128 n][64 k]    = 32 KB
  const int tid = threadIdx.x, lane = tid & 63, w = tid >> 6;
  const int wm = w >> 1, wn = w & 1;
  const int l15 = lane & 15, l4 = lane >> 4;
  const int bid = blockIdx.x;
  const int e  = bid & 7;
  const int s  = bid >> 3;       // 0..63
  const int nt = s >> 3;         // 0..7
  const int mt = s & 7;          // 0..7

  const _Float16* aSrc = hidden + ((size_t)((e * 8 + mt) * 64)) * 8192;
  const _Float16* bSrc = w2img  + ((size_t)((e * 8 + nt) * 64)) * 8192;

  f32x4 acc[2][4];
#pragma unroll
  for (int i = 0; i < 2; ++i)
#pragma unroll
    for (int j = 0; j < 4; ++j) acc[i][j] = (f32x4){0.f, 0.f, 0.f, 0.f};

  for (int kt = 0; kt < 32; ++kt) {
    __syncthreads();
#pragma unroll
    for (int h = 0; h < 2; ++h) {
      const size_t ko = (size_t)(2 * kt + h) * 8192;
#pragma unroll
      for (int i = 0; i < 2; ++i) {
        cp16(&As[h][(i * 512 + tid) * 8], aSrc + ko + (i * 512 + tid) * 8);
        cp16(&Bs[h][(i * 512 + tid) * 8], bSrc + ko + (i * 512 + tid) * 8);
      }
    }
    __syncthreads();
#pragma unroll
    for (int ks = 0; ks < 4; ++ks) {
      const int h  = ks >> 1;
      const int gq = (ks & 1) * 4 + l4;
      f16x8 af[2], bf[4];
#pragma unroll
      for (int fm = 0; fm < 2; ++fm) {
        const int m = wm * 32 + fm * 16 + l15;
        af[fm] = *(const f16x8*)&As[h][m * 64 + (gq ^ (m & 7)) * 8];
      }
#pragma unroll
      for (int fn = 0; fn < 4; ++fn) {
        const int n = wn * 64 + fn * 16 + l15;
        bf[fn] = *(const f16x8*)&Bs[h][n * 64 + (gq ^ (n & 7)) * 8];
      }
#pragma unroll
      for (int fm = 0; fm < 2; ++fm)
#pragma unroll
        for (int fn = 0; fn < 4; ++fn)
          acc[fm][fn] = __builtin_amdgcn_mfma_f32_16x16x32_f16(af[fm], bf[fn], acc[fm][fn], 0, 0, 0);
    }
  }

  // epilogue: scatter (acc + b2) * topw to token rows
  int   toks[2][4];
  float wgts[2][4];
#pragma unroll
  for (int fm = 0; fm < 2; ++fm)
#pragma unroll
    for (int r = 0; r < 4; ++r) {
      const int row = mt * 128 + wm * 32 + fm * 16 + l4 * 4 + r;
      const int tk = idx[e * CAP + row];
      toks[fm][r] = tk;
      wgts[fm][r] = (tk < T_TOK) ? topw[tk] : 0.f;
    }
#pragma unroll
  for (int fn = 0; fn < 4; ++fn) {
    const int dcol = nt * 128 + wn * 64 + fn * 16 + l15;
    const float bb = b2[e * DIM + dcol];
#pragma unroll
    for (int fm = 0; fm < 2; ++fm)
#pragma unroll
      for (int r = 0; r < 4; ++r) {
        const int tk = toks[fm][r];
        if (tk < T_TOK)
          out[(size_t)tk * DIM + dcol] = (acc[fm][fn][r] + bb) * wgts[fm][r];
      }
  }
}

// ---------------------------------------------------------------------------
extern "C" void kernel_launch(void* const* d_in, const int* in_sizes, int n_in,
                              void* d_out, int out_size, void* d_ws, size_t ws_size,
                              hipStream_t stream)
{
  const float* x  = (const float*)d_in[0];
  const float* Wr = (const float*)d_in[1];
  const float* W1 = (const float*)d_in[2];
  const float* b1 = (const float*)d_in[3];
  const float* W2 = (const float*)d_in[4];
  const float* b2 = (const float*)d_in[5];
  float* out = (float*)d_out;
  char* ws = (char*)d_ws;

  const size_t HID  = 67108864ull;  // hidden image fp16
  const size_t WIMG = 67108864ull;  // W1 image
  const size_t XG   = 16777216ull;  // gathered-x image fp16

  _Float16* hidden = (_Float16*)ws;
  _Float16* w1img  = (_Float16*)(ws + HID);
  _Float16* xg     = (_Float16*)(ws + HID + WIMG);
  int*   idx  = (int*)(ws + HID + WIMG + XG);
  int*   top  = idx + 8192;
  float* topw = (float*)(top + 8192);
  _Float16* w2img = (_Float16*)(ws + HID + WIMG + XG + 3 * 32768ull);
  int* dropCnt  = (int*)(ws + HID + WIMG + XG + 3 * 32768ull + WIMG);
  int* dropList = dropCnt + 16;

  moe_router<<<T_TOK / 16, 256, 0, stream>>>(x, Wr, top, topw);
  moe_scan<<<1, 1024, 0, stream>>>(top, idx, dropCnt, dropList);
  zero_drops<<<128, 256, 0, stream>>>(dropCnt, dropList, out);
  xg_w1<<<512 + 2048, 256, 0, stream>>>(x, idx, xg, W1, w1img);
  gemm1_w2<<<1024 + 4096, 512, 0, stream>>>(xg, w1img, b1, hidden, W2, w2img);
  gemm2_big<<<NE * 8 * 8, 512, 0, stream>>>(hidden, w2img, b2, idx, topw, out);
}

// Round 21
// 280.815 us; speedup vs baseline: 1.1093x; 1.0188x over previous
//
#include <hip/hip_runtime.h>
#include <hip/hip_bf16.h>
#include <hip/hip_fp16.h>

typedef _Float16 f16x8 __attribute__((ext_vector_type(8)));
typedef _Float16 f16x4 __attribute__((ext_vector_type(4)));
typedef float f32x4 __attribute__((ext_vector_type(4)));

#define T_TOK 8192
#define DIM   1024
#define FF    4096
#define NE    8
#define CAP   1024

// ---------------------------------------------------------------------------
// async global->LDS 16B copy. LDS dest = wave-uniform base + lane*16 (HW);
// global src is per-lane.
// ---------------------------------------------------------------------------
__device__ __forceinline__ void cp16(_Float16* lds, const _Float16* g) {
  __builtin_amdgcn_global_load_lds(
      (const __attribute__((address_space(1))) unsigned int*)(const void*)g,
      (__attribute__((address_space(3))) unsigned int*)(void*)lds, 16, 0, 0);
}

// ---------------------------------------------------------------------------
// Router (proven). Block 0 also zeroes dropCnt (router strictly precedes the
// 8-block scan in stream order -> race-free, deterministic, graph-safe).
// ---------------------------------------------------------------------------
__global__ __launch_bounds__(256) void moe_router(
    const float* __restrict__ x, const float* __restrict__ Wr,
    int* __restrict__ top, float* __restrict__ topw,
    int* __restrict__ dropCnt)
{
  __shared__ float sWr[DIM * 9];
  const int tid = threadIdx.x;
  if (blockIdx.x == 0 && tid == 0) dropCnt[0] = 0;
  for (int i = tid; i < DIM * NE; i += 256) {
    int d = i >> 3, e = i & 7;
    sWr[d * 9 + e] = Wr[i];
  }
  __syncthreads();
  const int lane = tid & 63, w = tid >> 6;
  for (int t = 0; t < 4; ++t) {
    const int token = blockIdx.x * 16 + w * 4 + t;
    float acc[8] = {0.f, 0.f, 0.f, 0.f, 0.f, 0.f, 0.f, 0.f};
    for (int j = 0; j < 16; ++j) {
      float xv = x[(size_t)token * DIM + j * 64 + lane];
      const float* wr = &sWr[(j * 64 + lane) * 9];
#pragma unroll
      for (int e = 0; e < 8; ++e) acc[e] += xv * wr[e];
    }
#pragma unroll
    for (int e = 0; e < 8; ++e) {
#pragma unroll
      for (int off = 32; off > 0; off >>= 1)
        acc[e] += __shfl_xor(acc[e], off, 64);
    }
    if (lane == 0) {
      float m = acc[0];
#pragma unroll
      for (int e = 1; e < 8; ++e) m = fmaxf(m, acc[e]);
      float s = 0.f;
#pragma unroll
      for (int e = 0; e < 8; ++e) s += expf(acc[e] - m);
      int bi = 0; float bv = acc[0];
#pragma unroll
      for (int e = 1; e < 8; ++e) { if (acc[e] > bv) { bv = acc[e]; bi = e; } }
      top[token]  = bi;
      topw[token] = 1.0f / s;
    }
  }
}

// ---------------------------------------------------------------------------
// Parallel order-preserving dispatch: 8 blocks, one expert each. Block e
// performs the stable compaction of tokens with top==e (1 ballot/chunk vs 8).
// Dropped tokens (per-expert rank >= CAP) recorded via device-scope atomics;
// list order is non-deterministic but zero_drops is order-insensitive.
// ---------------------------------------------------------------------------
__global__ __launch_bounds__(1024) void moe_scan8(
    const int* __restrict__ top, int* __restrict__ idx,
    int* __restrict__ dropCnt, int* __restrict__ dropList)
{
  __shared__ int wcnt[16];
  __shared__ int wpre[16];
  __shared__ int running;
  const int e = blockIdx.x;
  const int tid = threadIdx.x, lane = tid & 63, w = tid >> 6;
  for (int i = tid; i < CAP; i += 1024) idx[e * CAP + i] = T_TOK;
  if (tid == 0) running = 0;
  __syncthreads();
  for (int chunk = 0; chunk < T_TOK / 1024; ++chunk) {
    const int tok = chunk * 1024 + tid;
    const bool mine = (top[tok] == e);
    const unsigned long long m = __ballot(mine);
    if (lane == 0) wcnt[w] = __builtin_popcountll(m);
    const int rankw = __builtin_popcountll(m & ((1ull << lane) - 1ull));
    __syncthreads();
    if (tid == 0) {
      int s = running;
#pragma unroll
      for (int ww = 0; ww < 16; ++ww) { wpre[ww] = s; s += wcnt[ww]; }
      running = s;
    }
    __syncthreads();
    if (mine) {
      const int rank = wpre[w] + rankw;
      if (rank < CAP) idx[e * CAP + rank] = tok;
      else { const int p = atomicAdd(dropCnt, 1); dropList[p] = tok; }
    }
  }
}

// ---------------------------------------------------------------------------
// Zero only the dropped-token out rows (256 thr x f32x4 = one full row).
// ---------------------------------------------------------------------------
__global__ __launch_bounds__(256) void zero_drops(
    const int* __restrict__ dropCnt, const int* __restrict__ dropList,
    float* __restrict__ out)
{
  const int n = dropCnt[0];
  const f32x4 z = {0.f, 0.f, 0.f, 0.f};
  for (int i = blockIdx.x; i < n; i += gridDim.x) {
    const int tok = dropList[i];
    *(f32x4*)&out[(size_t)tok * DIM + threadIdx.x * 4] = z;
  }
}

// ---------------------------------------------------------------------------
// Fused: xg image (bid < 512) + W1 image (bid >= 512). (proven)
// ---------------------------------------------------------------------------
__global__ __launch_bounds__(256) void xg_w1(
    const float* __restrict__ x, const int* __restrict__ idx,
    _Float16* __restrict__ xgimg,
    const float* __restrict__ W1, _Float16* __restrict__ w1img)
{
  __shared__ _Float16 sT[64 * 256];   // 32 KB (W1 path)
  const int tid = threadIdx.x, bid = blockIdx.x;
  if (bid < 512) {
    const int kt = bid & 15, mt = (bid >> 4) & 3, e = bid >> 6;
    const int tok = idx[e * CAP + mt * 256 + tid];
    _Float16* dst = xgimg + (size_t)((e * 4 + mt) * 16 + kt) * 16384 + (size_t)tid * 64;
    if (tok < T_TOK) {
      const f32x4* src = (const f32x4*)(x + (size_t)tok * DIM + kt * 64);
      f32x4 v[16];
#pragma unroll
      for (int i = 0; i < 16; ++i) v[i] = src[i];
#pragma unroll
      for (int g = 0; g < 8; ++g) {
        f16x8 h;
#pragma unroll
        for (int c = 0; c < 4; ++c) {
          h[c]     = (_Float16)v[2 * g][c];
          h[4 + c] = (_Float16)v[2 * g + 1][c];
        }
        *(f16x8*)(dst + ((g ^ (tid & 7)) * 8)) = h;
      }
    } else {
      f16x8 z = {};
#pragma unroll
      for (int g = 0; g < 8; ++g) *(f16x8*)(dst + g * 8) = z;
    }
    return;
  }
  const int b = bid - 512;                      // 0..2047
  const int kt = b & 15, nt = (b >> 4) & 15, e = b >> 8;
  const float* src = W1 + (size_t)e * DIM * FF + (size_t)(kt * 64) * FF + nt * 256;
#pragma unroll
  for (int i = 0; i < 16; ++i) {
    const int q = i * 256 + tid;
    const int row = q >> 6, c4 = (q & 63) * 4;
    f32x4 u = *(const f32x4*)(src + (size_t)row * FF + c4);
    f16x4 h;
#pragma unroll
    for (int c = 0; c < 4; ++c) h[c] = (_Float16)u[c];
    *(f16x4*)&sT[row * 256 + c4] = h;
  }
  __syncthreads();
  _Float16* dst = w1img + (size_t)b * 16384;
  const int n = tid;
#pragma unroll
  for (int i = 0; i < 8; ++i) {
    const int g = i ^ (n & 7);
    f16x8 h;
#pragma unroll
    for (int j = 0; j < 8; ++j) h[j] = sT[(g * 8 + j) * 256 + n];
    *(f16x8*)(dst + (size_t)n * 64 + i * 8) = h;
  }
}

// ---------------------------------------------------------------------------
// gemm1 128x256 (bid < 1024) + W2 image (bid >= 1024, 512-thr proven body).
// (verbatim round-15/19/20 best)
// ---------------------------------------------------------------------------
__global__ __launch_bounds__(512, 4) void gemm1_w2(
    const _Float16* __restrict__ xg, const _Float16* __restrict__ w1img,
    const float* __restrict__ b1, _Float16* __restrict__ hidden,
    const float* __restrict__ W2, _Float16* __restrict__ w2img)
{
  __shared__ _Float16 SH[24576];    // 48 KB: As = SH[0..8191], Bs = SH[8192..]
  _Float16* As = SH;
  _Float16* Bs = SH + 8192;
  const int tid = threadIdx.x;
  const int bid = blockIdx.x;

  if (bid >= 1024) {
    // ---- W2 image block (round-12 proven 512-thr body) ----
    const int b = bid - 1024;                   // 0..4095
    const int kt = b & 63, nt = (b >> 6) & 7, e = b >> 9;
    const float* src = W2 + (size_t)e * FF * DIM + (size_t)(kt * 64) * DIM + nt * 128;
    _Float16* sT = As;                          // [64][128] bounce (16 KB)
#pragma unroll
    for (int i = 0; i < 4; ++i) {
      const int q = i * 512 + tid;
      const int row = q >> 5, c4 = (q & 31) * 4;
      f32x4 u = *(const f32x4*)(src + (size_t)row * DIM + c4);
      f16x4 h;
#pragma unroll
      for (int c = 0; c < 4; ++c) h[c] = (_Float16)u[c];
      *(f16x4*)&sT[row * 128 + c4] = h;
    }
    __syncthreads();
    _Float16* dst = w2img + (size_t)b * 8192;
    const int n = tid & 127, gb = (tid >> 7) * 2;
#pragma unroll
    for (int i = 0; i < 2; ++i) {
      const int gpos = gb + i, g = gpos ^ (n & 7);
      f16x8 h;
#pragma unroll
      for (int j = 0; j < 8; ++j) h[j] = sT[(g * 8 + j) * 128 + n];
      *(f16x8*)(dst + (size_t)n * 64 + gpos * 8) = h;
    }
    return;
  }

  // ---- gemm1 block: 128 rows x 256 cols ----
  const int lane = tid & 63, w = tid >> 6;
  const int wm = w >> 2, wn = w & 3;            // 2M x 4N, wave = 64x64
  const int l15 = lane & 15, l4 = lane >> 4;
  const int e  = bid & 7;                       // expert -> XCD pin
  const int s  = bid >> 3;                      // 0..127
  const int mt = s & 7;                         // 128-row tile (8)
  const int nt = s >> 3;                        // 256-col F tile (16)

  const _Float16* aSrc = xg + ((size_t)(e * 4 + (mt >> 1)) * 16) * 16384
                         + (size_t)(mt & 1) * 8192;
  const _Float16* bSrc = w1img + (size_t)(e * 256 + nt * 16) * 16384;

  f32x4 acc[4][4];
#pragma unroll
  for (int i = 0; i < 4; ++i)
#pragma unroll
    for (int j = 0; j < 4; ++j) acc[i][j] = (f32x4){0.f, 0.f, 0.f, 0.f};

  for (int kt = 0; kt < 16; ++kt) {
    __syncthreads();
#pragma unroll
    for (int i = 0; i < 2; ++i)
      cp16(&As[(i * 512 + tid) * 8], aSrc + (size_t)kt * 16384 + (i * 512 + tid) * 8);
#pragma unroll
    for (int i = 0; i < 4; ++i)
      cp16(&Bs[(i * 512 + tid) * 8], bSrc + (size_t)kt * 16384 + (i * 512 + tid) * 8);
    __syncthreads();
#pragma unroll
    for (int ks = 0; ks < 2; ++ks) {
      const int gq = ks * 4 + l4;
      f16x8 af[4], bf[4];
#pragma unroll
      for (int fm = 0; fm < 4; ++fm) {
        const int m = wm * 64 + fm * 16 + l15;                 // 0..127
        af[fm] = *(const f16x8*)&As[m * 64 + (gq ^ (m & 7)) * 8];
      }
#pragma unroll
      for (int fn = 0; fn < 4; ++fn) {
        const int n = wn * 64 + fn * 16 + l15;                 // 0..255
        bf[fn] = *(const f16x8*)&Bs[n * 64 + (gq ^ (n & 7)) * 8];
      }
#pragma unroll
      for (int fm = 0; fm < 4; ++fm)
#pragma unroll
        for (int fn = 0; fn < 4; ++fn)
          acc[fm][fn] = __builtin_amdgcn_mfma_f32_16x16x32_f16(af[fm], bf[fn], acc[fm][fn], 0, 0, 0);
    }
  }

  // ---- epilogue: LDS-bounce transpose, relu(acc+b1) -> hidden image ----
  __syncthreads();
  float* sw = (float*)SH + (size_t)w * 1088;    // 4.25 KB scratch per wave
  const int ftile = nt * 4 + wn;                // 0..63
  const size_t tbase = ((size_t)((e * 8 + mt) * 64) + ftile) * 8192;
  const int fbase = nt * 256 + wn * 64;
#pragma unroll
  for (int fm = 0; fm < 4; ++fm) {
#pragma unroll
    for (int fn = 0; fn < 4; ++fn) {
      const int floc = fn * 16 + l15;
      const float bb = b1[e * FF + fbase + floc];
      f32x4 v;
#pragma unroll
      for (int r = 0; r < 4; ++r) v[r] = fmaxf(acc[fm][fn][r] + bb, 0.f);
      *(f32x4*)&sw[floc * 17 + l4 * 4] = v;
    }
    const int p = l15;
    const int mrow = wm * 64 + fm * 16 + p;     // 0..127 within image tile
#pragma unroll
    for (int it = 0; it < 2; ++it) {
      const int g = it * 4 + l4;
      f16x8 h;
#pragma unroll
      for (int j = 0; j < 8; ++j) h[j] = (_Float16)sw[(g * 8 + j) * 17 + p];
      *(f16x8*)&hidden[tbase + (size_t)mrow * 64 + (g ^ (mrow & 7)) * 8] = h;
    }
  }
}

// ---------------------------------------------------------------------------
// GEMM2 BK=128 (round-19/20 proven): out[tok] = (hidden @ W2img + b2) * topw.
// 128x128xBK128, 512 thr (8 waves 4Mx2N, acc[2][4]), 64 KB single-buffer,
// 2 blocks/CU, 32 drains/block, 32 MFMA per barrier pair.
// bid = e + 8*s: expert pinned to XCD.
// ---------------------------------------------------------------------------
__global__ __launch_bounds__(512, 4) void gemm2_big(
    const _Float16* __restrict__ hidden, const _Float16* __restrict__ w2img,
    const float* __restrict__ b2, const int* __restrict__ idx,
    const float* __restrict__ topw, float* __restrict__ out)
{
  __shared__ _Float16 As[2][8192];   // [k-half][128 rows][64 k] = 32 KB
  __shared__ _Float16 Bs[2][8192];   // [k-half][128 n][64 k]    = 32 KB
  const int tid = threadIdx.x, lane = tid & 63, w = tid >> 6;
  const int wm = w >> 1, wn = w & 1;
  const int l15 = lane & 15, l4 = lane >> 4;
  const int bid = blockIdx.x;
  const int e  = bid & 7;
  const int s  = bid >> 3;       // 0..63
  const int nt = s >> 3;         // 0..7
  const int mt = s & 7;          // 0..7

  const _Float16* aSrc = hidden + ((size_t)((e * 8 + mt) * 64)) * 8192;
  const _Float16* bSrc = w2img  + ((size_t)((e * 8 + nt) * 64)) * 8192;

  f32x4 acc[2][4];
#pragma unroll
  for (int i = 0; i < 2; ++i)
#pragma unroll
    for (int j = 0; j < 4; ++j) acc[i][j] = (f32x4){0.f, 0.f, 0.f, 0.f};

  for (int kt = 0; kt < 32; ++kt) {
    __syncthreads();
#pragma unroll
    for (int h = 0; h < 2; ++h) {
      const size_t ko = (size_t)(2 * kt + h) * 8192;
#pragma unroll
      for (int i = 0; i < 2; ++i) {
        cp16(&As[h][(i * 512 + tid) * 8], aSrc + ko + (i * 512 + tid) * 8);
        cp16(&Bs[h][(i * 512 + tid) * 8], bSrc + ko + (i * 512 + tid) * 8);
      }
    }
    __syncthreads();
#pragma unroll
    for (int ks = 0; ks < 4; ++ks) {
      const int h  = ks >> 1;
      const int gq = (ks & 1) * 4 + l4;
      f16x8 af[2], bf[4];
#pragma unroll
      for (int fm = 0; fm < 2; ++fm) {
        const int m = wm * 32 + fm * 16 + l15;
        af[fm] = *(const f16x8*)&As[h][m * 64 + (gq ^ (m & 7)) * 8];
      }
#pragma unroll
      for (int fn = 0; fn < 4; ++fn) {
        const int n = wn * 64 + fn * 16 + l15;
        bf[fn] = *(const f16x8*)&Bs[h][n * 64 + (gq ^ (n & 7)) * 8];
      }
#pragma unroll
      for (int fm = 0; fm < 2; ++fm)
#pragma unroll
        for (int fn = 0; fn < 4; ++fn)
          acc[fm][fn] = __builtin_amdgcn_mfma_f32_16x16x32_f16(af[fm], bf[fn], acc[fm][fn], 0, 0, 0);
    }
  }

  // epilogue: scatter (acc + b2) * topw to token rows
  int   toks[2][4];
  float wgts[2][4];
#pragma unroll
  for (int fm = 0; fm < 2; ++fm)
#pragma unroll
    for (int r = 0; r < 4; ++r) {
      const int row = mt * 128 + wm * 32 + fm * 16 + l4 * 4 + r;
      const int tk = idx[e * CAP + row];
      toks[fm][r] = tk;
      wgts[fm][r] = (tk < T_TOK) ? topw[tk] : 0.f;
    }
#pragma unroll
  for (int fn = 0; fn < 4; ++fn) {
    const int dcol = nt * 128 + wn * 64 + fn * 16 + l15;
    const float bb = b2[e * DIM + dcol];
#pragma unroll
    for (int fm = 0; fm < 2; ++fm)
#pragma unroll
      for (int r = 0; r < 4; ++r) {
        const int tk = toks[fm][r];
        if (tk < T_TOK)
          out[(size_t)tk * DIM + dcol] = (acc[fm][fn][r] + bb) * wgts[fm][r];
      }
  }
}

// ---------------------------------------------------------------------------
extern "C" void kernel_launch(void* const* d_in, const int* in_sizes, int n_in,
                              void* d_out, int out_size, void* d_ws, size_t ws_size,
                              hipStream_t stream)
{
  const float* x  = (const float*)d_in[0];
  const float* Wr = (const float*)d_in[1];
  const float* W1 = (const float*)d_in[2];
  const float* b1 = (const float*)d_in[3];
  const float* W2 = (const float*)d_in[4];
  const float* b2 = (const float*)d_in[5];
  float* out = (float*)d_out;
  char* ws = (char*)d_ws;

  const size_t HID  = 67108864ull;  // hidden image fp16
  const size_t WIMG = 67108864ull;  // W1 image
  const size_t XG   = 16777216ull;  // gathered-x image fp16

  _Float16* hidden = (_Float16*)ws;
  _Float16* w1img  = (_Float16*)(ws + HID);
  _Float16* xg     = (_Float16*)(ws + HID + WIMG);
  int*   idx  = (int*)(ws + HID + WIMG + XG);
  int*   top  = idx + 8192;
  float* topw = (float*)(top + 8192);
  _Float16* w2img = (_Float16*)(ws + HID + WIMG + XG + 3 * 32768ull);
  int* dropCnt  = (int*)(ws + HID + WIMG + XG + 3 * 32768ull + WIMG);
  int* dropList = dropCnt + 16;

  moe_router<<<T_TOK / 16, 256, 0, stream>>>(x, Wr, top, topw, dropCnt);
  moe_scan8<<<NE, 1024, 0, stream>>>(top, idx, dropCnt, dropList);
  zero_drops<<<128, 256, 0, stream>>>(dropCnt, dropList, out);
  xg_w1<<<512 + 2048, 256, 0, stream>>>(x, idx, xg, W1, w1img);
  gemm1_w2<<<1024 + 4096, 512, 0, stream>>>(xg, w1img, b1, hidden, W2, w2img);
  gemm2_big<<<NE * 8 * 8, 512, 0, stream>>>(hidden, w2img, b2, idx, topw, out);
}